// Round 6
// baseline (400.362 us; speedup 1.0000x reference)
//
#include <hip/hip_runtime.h>
#include <hip/hip_bf16.h>
#include <math.h>

#define NB 2
#define NC 256
#define HWIN 4096
#define NN 4096
#define ND 32
#define NHH 4
#define EPSV 1e-5f

typedef short short8 __attribute__((ext_vector_type(8)));
typedef float f32x4 __attribute__((ext_vector_type(4)));
typedef unsigned short u16;
typedef unsigned int u32;

// workspace offsets (float32 units)
#define OFF_T1   0          // 131072
#define OFF_Y1   131072     // 131072
#define OFF_T2   262144     // 524288
#define OFF_Y2   786432     // 524288
#define OFF_Q    1310720    // 524288 (bf16 x 1048576)
#define OFF_KT1  1835008    // 65536
#define OFF_VT1  1900544    // 65536
#define OFF_KT2  1966080    // 262144
#define OFF_VT2  2228224    // 262144
#define OFF_RCT1 2490368    // 40960
#define OFF_RCT2 2531328    // 163840
#define OFF_WT   2695168    // 131072  (kvw^T, f32 [c][o] 256x512)
#define OFF_QWT  2826240    // 32768   (qw^T,  f32 [c][oc] 256x128)
#define OFF_PO   2859008    // 2097152 (br2 partial O, u32-packed bf16 pairs)
#define OFF_PS   4956160    // 131072  (br2 partial ssum, [row][4])
// end 5087232 floats = 20.3 MB

#define QSCALE 0.2550437314857726f   // 1/sqrt(32) * log2(e)
#define LOG2E  1.4426950408889634f

__device__ __forceinline__ u16 f2bf(float x) {   // f32 -> bf16 RNE
  unsigned u = __float_as_uint(x);
  u += 0x7fffu + ((u >> 16) & 1u);
  return (u16)(u >> 16);
}

__device__ __forceinline__ u32 pk_bf16(float a, float b) {  // packed RNE cvt
  __hip_bfloat162 h = __float22bfloat162_rn(make_float2(a, b));
  u32 r; __builtin_memcpy(&r, &h, 4);
  return r;
}

__device__ __forceinline__ float keysw(float t) {  // Keys cubic, a=-0.5
  t = fabsf(t);
  float w;
  if (t < 1.f)       w = ((1.5f*t - 2.5f)*t)*t + 1.f;
  else if (t < 2.f)  w = ((-0.5f*t + 2.5f)*t - 4.f)*t + 2.f;
  else               w = 0.f;
  return w;
}

// ---------- device bodies ----------
template<int KS, int STR, int PAD, int OH>
__device__ __forceinline__ void dwconv_body(int idx, const float* __restrict__ x,
    const float* __restrict__ dww, const float* __restrict__ bn1,
    const float* __restrict__ pww, const float* __restrict__ bn2,
    float* __restrict__ tout) {
  const int hw = OH*OH;
  int s = idx % hw; int c = (idx/hw) % NC; int b = idx/(hw*NC);
  int oy = s / OH, ox = s % OH;
  const float* xp = x + (b*NC + c)*HWIN;
  const float* wp = dww + c*KS*KS;
  float acc = 0.f;
  #pragma unroll
  for (int ky = 0; ky < KS; ++ky) {
    int iy = oy*STR - PAD + ky;
    if (iy < 0 || iy >= 64) continue;
    #pragma unroll
    for (int kx = 0; kx < KS; ++kx) {
      int ix = ox*STR - PAD + kx;
      if (ix < 0 || ix >= 64) continue;
      acc += xp[iy*64 + ix] * wp[ky*KS + kx];
    }
  }
  float s1 = bn1[c] * rsqrtf(bn1[3*NC + c] + EPSV);
  float z = (acc - bn1[2*NC + c])*s1 + bn1[NC + c];
  z = fmaxf(z, 0.f);
  float s2 = bn2[c] * rsqrtf(bn2[3*NC + c] + EPSV);
  z = z * (pww[c]*s2) + (bn2[NC + c] - bn2[2*NC + c]*s2);
  tout[idx] = z;
}

__device__ __forceinline__ void rpe_body(int idx, const float* __restrict__ rpe,
                                         u16* __restrict__ rcT, int L, int ch) {
  int r = idx & 63; int l = (idx >> 6) % L; int b = idx / (64*L);
  float f = ((float)l + 0.5f)*(64.f/(float)L) - 0.5f;
  int i0 = (int)floorf(f) - 1;
  const float* rp = rpe + ((b*2 + ch)*64 + r)*64;
  float v = 0.f, wsum = 0.f;
  #pragma unroll
  for (int j = 0; j < 4; ++j) {
    int i = i0 + j;
    if (i >= 0 && i < 64) {
      float w = keysw(f - (float)i);
      v += w * rp[i]; wsum += w;
    }
  }
  rcT[((size_t)(b*L + l))*80 + 4 + r] = f2bf(v / wsum);
}

// ---------- stage 1: dwconv1 + dwconv2 + rpe1 + rpe2 + kvw^T + qw^T ----------
__global__ void __launch_bounds__(256) prep_kernel(
    const float* __restrict__ x,
    const float* __restrict__ dw1, const float* __restrict__ bn11,
    const float* __restrict__ pw1, const float* __restrict__ bn12, float* __restrict__ t1,
    const float* __restrict__ dw2, const float* __restrict__ bn21,
    const float* __restrict__ pw2, const float* __restrict__ bn22, float* __restrict__ t2,
    const float* __restrict__ rpe, u16* __restrict__ rct1, u16* __restrict__ rct2,
    const float* __restrict__ kvw, float* __restrict__ wt,
    const float* __restrict__ qw, float* __restrict__ qwt) {
  int blk = blockIdx.x;
  int t = threadIdx.x;
  if (blk < 512) {
    dwconv_body<7,4,3,16>(blk*256 + t, x, dw1, bn11, pw1, bn12, t1);
  } else if (blk < 2560) {
    dwconv_body<5,2,2,32>((blk-512)*256 + t, x, dw2, bn21, pw2, bn22, t2);
  } else if (blk < 2816) {
    rpe_body((blk-2560)*256 + t, rpe, rct1, 512, 0);
  } else if (blk < 3840) {
    rpe_body((blk-2816)*256 + t, rpe, rct2, 2048, 1);
  } else if (blk < 3968) {
    // kvw transpose: wt[c][o] = kvw[o][c]   (512x256 -> 256x512)
    int base = ((blk-3840)*256 + t)*4;
    float4 vv = *(const float4*)(kvw + base);
    int o = base >> 8, c = base & 255;
    wt[(c+0)*512 + o] = vv.x;
    wt[(c+1)*512 + o] = vv.y;
    wt[(c+2)*512 + o] = vv.z;
    wt[(c+3)*512 + o] = vv.w;
  } else {
    // qw transpose: qwt[c][oc] = qw[oc][c]  (128x256 -> 256x128)
    int base = ((blk-3968)*256 + t)*4;
    float4 vv = *(const float4*)(qw + base);
    int oc = base >> 8, c = base & 255;
    qwt[(c+0)*128 + oc] = vv.x;
    qwt[(c+1)*128 + oc] = vv.y;
    qwt[(c+2)*128 + oc] = vv.z;
    qwt[(c+3)*128 + oc] = vv.w;
  }
}

// ---------- stage 2: local 3x3 dw (both) + q 1x1 conv ----------
template<int OH>
__device__ __forceinline__ void local_body(int idx, const float* __restrict__ tin,
    const float* __restrict__ lw, const float* __restrict__ lb, float* __restrict__ yout) {
  const int hw = OH*OH;
  int s = idx % hw; int c = (idx/hw) % NC; int b = idx/(hw*NC);
  int oy = s/OH, ox = s%OH;
  const float* tp = tin + (b*NC + c)*hw;
  const float* wp = lw + c*9;
  float acc = lb[c];
  #pragma unroll
  for (int ky = 0; ky < 3; ++ky) {
    int iy = oy - 1 + ky;
    if (iy < 0 || iy >= OH) continue;
    #pragma unroll
    for (int kx = 0; kx < 3; ++kx) {
      int ix = ox - 1 + kx;
      if (ix < 0 || ix >= OH) continue;
      acc += tp[iy*OH + ix]*wp[ky*3 + kx];
    }
  }
  yout[idx] = acc + tp[s];
}

__global__ void __launch_bounds__(256) local_kernel(
    const float* __restrict__ t1, const float* __restrict__ t2,
    const float* __restrict__ lw, const float* __restrict__ lb,
    float* __restrict__ y1, float* __restrict__ y2,
    const float* __restrict__ x, const float* __restrict__ qwt,
    const float* __restrict__ qb, u16* __restrict__ q) {
  int blk = blockIdx.x, t = threadIdx.x;
  if (blk < 512)       { local_body<16>(blk*256 + t, t1, lw, lb, y1); return; }
  else if (blk < 2560) { local_body<32>((blk-512)*256 + t, t2, lw, lb, y2); return; }
  // ---- q conv: lanes = 64 spatial, wave = head (wave-uniform weight reads) ----
  int blk2 = blk - 2560;             // 0..127
  int b  = blk2 >> 6;
  int n0 = (blk2 & 63) * 64;
  int wv = t >> 6, lane = t & 63;    // wv = head 0..3
  const float* xb = x + (size_t)b*NC*HWIN + n0 + lane;
  const float* wb = qwt + 32*wv;     // row c: wb[c*128 + i], wave-uniform
  float acc[32];
  {
    const float4* qb4 = (const float4*)(qb + 32*wv);
    #pragma unroll
    for (int j = 0; j < 8; ++j) {
      float4 v = qb4[j];
      acc[4*j] = v.x; acc[4*j+1] = v.y; acc[4*j+2] = v.z; acc[4*j+3] = v.w;
    }
  }
  #pragma unroll 2
  for (int c = 0; c < NC; ++c) {
    float xv = xb[(size_t)c*HWIN];
    const float4* w4 = (const float4*)(wb + c*128);
    #pragma unroll
    for (int j = 0; j < 8; ++j) {
      float4 wq = w4[j];
      acc[4*j]   += wq.x*xv; acc[4*j+1] += wq.y*xv;
      acc[4*j+2] += wq.z*xv; acc[4*j+3] += wq.w*xv;
    }
  }
  u16* qp = q + (((size_t)(b*NHH + wv))*NN + n0 + lane)*ND;
  #pragma unroll
  for (int j = 0; j < 4; ++j) {
    uint4 pkd = make_uint4(pk_bf16(acc[8*j]*QSCALE,   acc[8*j+1]*QSCALE),
                           pk_bf16(acc[8*j+2]*QSCALE, acc[8*j+3]*QSCALE),
                           pk_bf16(acc[8*j+4]*QSCALE, acc[8*j+5]*QSCALE),
                           pk_bf16(acc[8*j+6]*QSCALE, acc[8*j+7]*QSCALE));
    ((uint4*)qp)[j] = pkd;
  }
}

// ---------- stage 3: kv 1x1 conv (transposed weights), both branches ----------
__global__ void __launch_bounds__(256) kv_kernel(
    const float* __restrict__ y1, const float* __restrict__ y2,
    const float* __restrict__ wt, const float* __restrict__ kvb,
    u16* __restrict__ kt1, u16* __restrict__ vt1,
    u16* __restrict__ kt2, u16* __restrict__ vt2) {
  __shared__ float yl[NC*4];
  int blk = blockIdx.x, t = threadIdx.x;
  const float* y; u16 *kT, *vT; int hw, b, s0;
  if (blk < 128) { y = y1; kT = kt1; vT = vt1; hw = 256;  b = blk >> 6;  s0 = (blk & 63)*4; }
  else { int v = blk-128; y = y2; kT = kt2; vT = vt2; hw = 1024; b = v >> 8; s0 = (v & 255)*4; }
  #pragma unroll
  for (int j = 0; j < 4; ++j) {
    int idx = t + 256*j;
    int c = idx >> 2, i = idx & 3;
    yl[idx] = y[(b*NC + c)*hw + s0 + i];
  }
  __syncthreads();
  int L = 2*hw;
  for (int half = 0; half < 2; ++half) {
    int o = t + half*256;
    const float* wr = wt + o;        // column o of kvw^T, stride 512
    float bias = kvb[o];
    float acc[4];
    #pragma unroll
    for (int i = 0; i < 4; ++i) acc[i] = bias;
    #pragma unroll 4
    for (int c = 0; c < NC; ++c) {
      float w = wr[c*512];
      #pragma unroll
      for (int i = 0; i < 4; ++i) acc[i] += w*yl[c*4 + i];
    }
    int oc = o & 255;
    int hh2 = oc >> 6, r = oc & 63, d = r >> 1, e = r & 1;
    if (half == 0) {
      u16* kp = kT + ((size_t)((b*NHH + hh2)*L + e*hw + s0))*ND + d;
      #pragma unroll
      for (int i = 0; i < 4; ++i) kp[i*ND] = f2bf(acc[i]);
    } else {
      u16* vp = vT + ((size_t)((b*NHH + hh2)*ND + d))*L + e*hw + s0;
      #pragma unroll
      for (int i = 0; i < 4; ++i) vp[i] = f2bf(acc[i]);
    }
  }
}

// ---------- stage 4: MFMA flash attention, max-free softmax ----------
// blocks [0,512): branch1 full L=512, direct write.
// blocks [512,2560): branch2, one of 4 L-chunks; writes bf16 partial O + ssum.
__global__ void __launch_bounds__(256) attn_kernel(
    const u16* __restrict__ qbf,
    const u16* __restrict__ kt1, const u16* __restrict__ vt1, const u16* __restrict__ rct1,
    const u16* __restrict__ kt2, const u16* __restrict__ vt2, const u16* __restrict__ rct2,
    u32* __restrict__ po32, float* __restrict__ ps,
    float* __restrict__ out) {
  __shared__ u32 pbuf_all[4][16*36];   // per-wave P^T tile, u16-stride 72
  int u = blockIdx.x;
  int br, b, hh, rb, chunk;
  if (u < 512) { br = 0; b = u >> 8; hh = (u >> 6) & 3; rb = u & 63; chunk = 0; }
  else { int v = u - 512; br = 1; chunk = v & 3; rb = (v >> 2) & 63; hh = (v >> 8) & 3; b = v >> 10; }
  int L = br ? 2048 : 512;
  const u16* kT  = br ? kt2 : kt1;
  const u16* vT  = br ? vt2 : vt1;
  const u16* rcT = br ? rct2 : rct1;
  int l0base = chunk * 512;
  int tid = threadIdx.x;
  int w = tid >> 6, lane = tid & 63;
  int g = lane >> 4, lo = lane & 15;
  u32* pbuf = pbuf_all[w];
  u16* pbuf16 = (u16*)pbuf;
  int n = rb*64 + w*16 + lo;

  const u16* kbase = kT + (size_t)(b*NHH + hh)*L*ND;
  const u16* vbase = vT + (size_t)(b*NHH + hh)*ND*L;
  const u16* rcTb  = rcT + (size_t)b*L*80;

  // Q B-frag (pre-scaled by 1/sqrt(32)*log2e)
  short8 qf = *(const short8*)(qbf + (((size_t)(b*NHH + hh))*NN + n)*ND + 8*g);

  // tap-weight B-frag for RPE ext-MFMA
  float fr = ((float)n + 0.5f)*(1.f/64.f) - 0.5f;
  int ri0 = (int)floorf(fr) - 1;
  int a = (w < 2) ? rb - 2 : rb - 1;     // wave-uniform floor(fr(q0)) - 1
  int rmin = a & ~3;
  float wr4[4]; float wsum = 0.f;
  #pragma unroll
  for (int j = 0; j < 4; ++j) {
    int i = ri0 + j;
    float wv = (i >= 0 && i < 64) ? keysw(fr - (float)i) : 0.f;
    wr4[j] = wv; wsum += wv;
  }
  float invw = LOG2E / wsum;
  float wt8[8];
  #pragma unroll
  for (int s = 0; s < 8; ++s) {
    float acc = 0.f;
    #pragma unroll
    for (int j = 0; j < 4; ++j)
      acc += (ri0 + j - rmin == s) ? wr4[j]*invw : 0.f;
    wt8[s] = acc;
  }
  short8 wtf;
  {
    u32 p0 = pk_bf16(wt8[0], wt8[1]), p1 = pk_bf16(wt8[2], wt8[3]);
    u32 p2 = pk_bf16(wt8[4], wt8[5]), p3 = pk_bf16(wt8[6], wt8[7]);
    uint4 uu = make_uint4(p0, p1, p2, p3);
    wtf = __builtin_bit_cast(short8, uu);
    if (g != 0) wtf = (short8)0;
  }
  const u16* rcrow0 = rcTb + (rmin + 4);

  const f32x4 zero = {0.f, 0.f, 0.f, 0.f};
  float ssum = 0.f;
  f32x4 o0 = zero, o1 = zero;

  for (int lt = 0; lt < 8; ++lt) {
    int l0 = l0base + lt*64;
    f32x4 s4[4];
    #pragma unroll
    for (int c = 0; c < 4; ++c) {
      const u16* arow = rcrow0 + (size_t)(l0 + 16*c + lo)*80;
      uint2 ra = *(const uint2*)arow;
      uint2 rb2 = *(const uint2*)(arow + 4);
      uint4 uu = make_uint4(ra.x, ra.y, rb2.x, rb2.y);
      short8 rcf = __builtin_bit_cast(short8, uu);
      f32x4 accr = __builtin_amdgcn_mfma_f32_16x16x32_bf16(rcf, wtf, zero, 0, 0, 0);
      short8 kf = *(const short8*)(kbase + (size_t)(l0 + 16*c + lo)*ND + 8*g);
      s4[c] = __builtin_amdgcn_mfma_f32_16x16x32_bf16(kf, qf, accr, 0, 0, 0);
    }
    // ---- max-free softmax: p = exp2(s) directly (scores bounded ~|10|) ----
    float psum = 0.f;
    u32 pk[8];
    #pragma unroll
    for (int c = 0; c < 4; ++c) {
      float p0 = exp2f(s4[c][0]), p1 = exp2f(s4[c][1]);
      float p2 = exp2f(s4[c][2]), p3 = exp2f(s4[c][3]);
      psum += (p0 + p1) + (p2 + p3);
      pk[2*c]   = pk_bf16(p0, p1);
      pk[2*c+1] = pk_bf16(p2, p3);
    }
    ssum += psum;
    #pragma unroll
    for (int c = 0; c < 4; ++c)
      *(uint2*)(pbuf + lo*36 + 8*c + 2*g) = make_uint2(pk[2*c], pk[2*c+1]);
    #pragma unroll
    for (int kc = 0; kc < 2; ++kc) {
      short8 pf  = *(const short8*)(pbuf16 + lo*72 + 32*kc + 8*g);
      short8 vf0 = *(const short8*)(vbase + (size_t)(lo)*L      + l0 + 32*kc + 8*g);
      short8 vf1 = *(const short8*)(vbase + (size_t)(16 + lo)*L + l0 + 32*kc + 8*g);
      o0 = __builtin_amdgcn_mfma_f32_16x16x32_bf16(vf0, pf, o0, 0, 0, 0);
      o1 = __builtin_amdgcn_mfma_f32_16x16x32_bf16(vf1, pf, o1, 0, 0, 0);
    }
  }
  ssum += __shfl_xor(ssum, 16, 64);
  ssum += __shfl_xor(ssum, 32, 64);
  if (br == 0) {
    float inv = 1.f/ssum;
    f32x4 w0 = o0*inv, w1 = o1*inv;
    float* op = out + ((size_t)((b*NC + hh*64 + rb)*64 + (w*16 + lo)))*64;
    *(f32x4*)(op + 4*g)      = w0;
    *(f32x4*)(op + 16 + 4*g) = w1;
  } else {
    int bh = b*NHH + hh;
    u32* pop = po32 + ((size_t)(bh*NN + n))*64 + chunk*16;
    pop[2*g]     = pk_bf16(o0[0], o0[1]);
    pop[2*g + 1] = pk_bf16(o0[2], o0[3]);
    pop[8 + 2*g]     = pk_bf16(o1[0], o1[1]);
    pop[8 + 2*g + 1] = pk_bf16(o1[2], o1[3]);
    if (g == 0) ps[((size_t)(bh*NN + n))*4 + chunk] = ssum;
  }
}

// ---------- stage 5: combine branch-2 chunk partials (linear now) ----------
__global__ void __launch_bounds__(256) combine_kernel(
    const u32* __restrict__ po32, const float* __restrict__ ps,
    float* __restrict__ out) {
  int row = blockIdx.x*256 + threadIdx.x;   // 0..32767 = bh*4096 + n
  float4 sv = *(const float4*)(ps + (size_t)row*4);
  float inv = 1.f/((sv.x + sv.y) + (sv.z + sv.w));
  const u32* pp = po32 + (size_t)row*64;
  float o[32];
  #pragma unroll
  for (int j = 0; j < 16; ++j) {
    u32 a0 = pp[j], a1 = pp[16+j], a2 = pp[32+j], a3 = pp[48+j];
    float lo0 = __uint_as_float(a0 << 16),        lo1 = __uint_as_float(a1 << 16);
    float lo2 = __uint_as_float(a2 << 16),        lo3 = __uint_as_float(a3 << 16);
    float hi0 = __uint_as_float(a0 & 0xffff0000u), hi1 = __uint_as_float(a1 & 0xffff0000u);
    float hi2 = __uint_as_float(a2 & 0xffff0000u), hi3 = __uint_as_float(a3 & 0xffff0000u);
    o[2*j]   = ((lo0 + lo1) + (lo2 + lo3))*inv;
    o[2*j+1] = ((hi0 + hi1) + (hi2 + hi3))*inv;
  }
  int bh = row >> 12, n = row & 4095;
  float* op = out + ((size_t)(((bh>>2)*NC + (bh&3)*64 + (n>>6))*64 + (n&63)))*64 + 32;
  #pragma unroll
  for (int j = 0; j < 8; ++j) {
    f32x4 v = {o[4*j], o[4*j+1], o[4*j+2], o[4*j+3]};
    *(f32x4*)(op + 4*j) = v;
  }
}

extern "C" void kernel_launch(void* const* d_in, const int* in_sizes, int n_in,
                              void* d_out, int out_size, void* d_ws, size_t ws_size,
                              hipStream_t stream) {
  const float* x    = (const float*)d_in[0];
  const float* rpe  = (const float*)d_in[1];
  const float* qw   = (const float*)d_in[2];
  const float* qb   = (const float*)d_in[3];
  const float* kvw  = (const float*)d_in[4];
  const float* kvb  = (const float*)d_in[5];
  const float* dw1  = (const float*)d_in[6];
  const float* bn11 = (const float*)d_in[7];
  const float* pw1  = (const float*)d_in[8];
  const float* bn12 = (const float*)d_in[9];
  const float* dw2  = (const float*)d_in[10];
  const float* bn21 = (const float*)d_in[11];
  const float* pw2  = (const float*)d_in[12];
  const float* bn22 = (const float*)d_in[13];
  const float* lw   = (const float*)d_in[14];
  const float* lb   = (const float*)d_in[15];
  float* out = (float*)d_out;
  float* ws  = (float*)d_ws;

  float* t1   = ws + OFF_T1;
  float* y1   = ws + OFF_Y1;
  float* t2   = ws + OFF_T2;
  float* y2   = ws + OFF_Y2;
  u16*   q    = (u16*)(ws + OFF_Q);
  u16*   kt1  = (u16*)(ws + OFF_KT1);
  u16*   vt1  = (u16*)(ws + OFF_VT1);
  u16*   kt2  = (u16*)(ws + OFF_KT2);
  u16*   vt2  = (u16*)(ws + OFF_VT2);
  u16*   rct1 = (u16*)(ws + OFF_RCT1);
  u16*   rct2 = (u16*)(ws + OFF_RCT2);
  float* wt   = ws + OFF_WT;
  float* qwt  = ws + OFF_QWT;
  u32*   po32 = (u32*)(ws + OFF_PO);
  float* ps   = ws + OFF_PS;

  hipLaunchKernelGGL(prep_kernel, dim3(4000), dim3(256), 0, stream,
                     x, dw1, bn11, pw1, bn12, t1, dw2, bn21, pw2, bn22, t2,
                     rpe, rct1, rct2, kvw, wt, qw, qwt);
  hipLaunchKernelGGL(local_kernel, dim3(2688), dim3(256), 0, stream,
                     t1, t2, lw, lb, y1, y2, x, qwt, qb, q);
  hipLaunchKernelGGL(kv_kernel, dim3(640), dim3(256), 0, stream,
                     y1, y2, wt, kvb, kt1, vt1, kt2, vt2);
  hipLaunchKernelGGL(attn_kernel, dim3(2560), dim3(256), 0, stream,
                     q, kt1, vt1, rct1, kt2, vt2, rct2, po32, ps, out);
  hipLaunchKernelGGL(combine_kernel, dim3(128), dim3(256), 0, stream,
                     po32, ps, out);
}

// Round 7
// 252.083 us; speedup vs baseline: 1.5882x; 1.5882x over previous
//
#include <hip/hip_runtime.h>
#include <hip/hip_bf16.h>
#include <math.h>

#define NB 2
#define NC 256
#define HWIN 4096
#define NN 4096
#define ND 32
#define NHH 4
#define EPSV 1e-5f

typedef short short8 __attribute__((ext_vector_type(8)));
typedef float f32x4 __attribute__((ext_vector_type(4)));
typedef unsigned short u16;
typedef unsigned int u32;

// workspace offsets (float32 units)
#define OFF_T1   0          // 131072
#define OFF_Y1   131072     // 131072
#define OFF_T2   262144     // 524288
#define OFF_Y2   786432     // 524288
#define OFF_Q    1310720    // 524288 (bf16 x 1048576)
#define OFF_KT1  1835008    // 65536
#define OFF_VT1  1900544    // 65536
#define OFF_KT2  1966080    // 262144
#define OFF_VT2  2228224    // 262144
#define OFF_RCT1 2490368    // 40960
#define OFF_RCT2 2531328    // 163840
#define OFF_WT   2695168    // 131072  (kvw^T, f32 [c][o] 256x512)
#define OFF_PO   2826240    // 2097152 (br2 partial O, u32-packed bf16 pairs)
#define OFF_PS   4923392    // 131072  (br2 partial ssum, [row][4])
// end 5054464 floats = 20.2 MB

#define QSCALE 0.2550437314857726f   // 1/sqrt(32) * log2(e)
#define LOG2E  1.4426950408889634f

__device__ __forceinline__ u16 f2bf(float x) {   // f32 -> bf16 RNE
  unsigned u = __float_as_uint(x);
  u += 0x7fffu + ((u >> 16) & 1u);
  return (u16)(u >> 16);
}

__device__ __forceinline__ u32 pk_bf16(float a, float b) {  // packed RNE cvt
  __hip_bfloat162 h = __float22bfloat162_rn(make_float2(a, b));
  u32 r; __builtin_memcpy(&r, &h, 4);
  return r;
}

__device__ __forceinline__ float keysw(float t) {  // Keys cubic, a=-0.5
  t = fabsf(t);
  float w;
  if (t < 1.f)       w = ((1.5f*t - 2.5f)*t)*t + 1.f;
  else if (t < 2.f)  w = ((-0.5f*t + 2.5f)*t - 4.f)*t + 2.f;
  else               w = 0.f;
  return w;
}

// ---------- device bodies ----------
template<int KS, int STR, int PAD, int OH>
__device__ __forceinline__ void dwconv_body(int idx, const float* __restrict__ x,
    const float* __restrict__ dww, const float* __restrict__ bn1,
    const float* __restrict__ pww, const float* __restrict__ bn2,
    float* __restrict__ tout) {
  const int hw = OH*OH;
  int s = idx % hw; int c = (idx/hw) % NC; int b = idx/(hw*NC);
  int oy = s / OH, ox = s % OH;
  const float* xp = x + (b*NC + c)*HWIN;
  const float* wp = dww + c*KS*KS;
  float acc = 0.f;
  #pragma unroll
  for (int ky = 0; ky < KS; ++ky) {
    int iy = oy*STR - PAD + ky;
    if (iy < 0 || iy >= 64) continue;
    #pragma unroll
    for (int kx = 0; kx < KS; ++kx) {
      int ix = ox*STR - PAD + kx;
      if (ix < 0 || ix >= 64) continue;
      acc += xp[iy*64 + ix] * wp[ky*KS + kx];
    }
  }
  float s1 = bn1[c] * rsqrtf(bn1[3*NC + c] + EPSV);
  float z = (acc - bn1[2*NC + c])*s1 + bn1[NC + c];
  z = fmaxf(z, 0.f);
  float s2 = bn2[c] * rsqrtf(bn2[3*NC + c] + EPSV);
  z = z * (pww[c]*s2) + (bn2[NC + c] - bn2[2*NC + c]*s2);
  tout[idx] = z;
}

__device__ __forceinline__ void rpe_body(int idx, const float* __restrict__ rpe,
                                         u16* __restrict__ rcT, int L, int ch) {
  int r = idx & 63; int l = (idx >> 6) % L; int b = idx / (64*L);
  float f = ((float)l + 0.5f)*(64.f/(float)L) - 0.5f;
  int i0 = (int)floorf(f) - 1;
  const float* rp = rpe + ((b*2 + ch)*64 + r)*64;
  float v = 0.f, wsum = 0.f;
  #pragma unroll
  for (int j = 0; j < 4; ++j) {
    int i = i0 + j;
    if (i >= 0 && i < 64) {
      float w = keysw(f - (float)i);
      v += w * rp[i]; wsum += w;
    }
  }
  rcT[((size_t)(b*L + l))*80 + 4 + r] = f2bf(v / wsum);
}

// ---------- stage 1: qconv + dwconv1 + dwconv2 + rpe1 + rpe2 + kvw^T ----------
__global__ void __launch_bounds__(256) prep_kernel(
    const float* __restrict__ x, const float* __restrict__ qw,
    const float* __restrict__ qb, u16* __restrict__ q,
    const float* __restrict__ dw1, const float* __restrict__ bn11,
    const float* __restrict__ pw1, const float* __restrict__ bn12, float* __restrict__ t1,
    const float* __restrict__ dw2, const float* __restrict__ bn21,
    const float* __restrict__ pw2, const float* __restrict__ bn22, float* __restrict__ t2,
    const float* __restrict__ rpe, u16* __restrict__ rct1, u16* __restrict__ rct2,
    const float* __restrict__ kvw, float* __restrict__ wt) {
  __shared__ float xl[NC*16];
  int blk = blockIdx.x;
  int t = threadIdx.x;
  if (blk < 512) {
    // ---- q 1x1 conv (16 spatial/block, 2 threads per oc) ----
    int b = blk >> 8;
    int n0 = (blk & 255) * 16;
    #pragma unroll
    for (int j = 0; j < 16; ++j) {
      int idx = t + 256*j;
      int c = idx >> 4, i = idx & 15;
      xl[idx] = x[(b*NC + c)*HWIN + n0 + i];
    }
    __syncthreads();
    int half = t >> 7, oc = t & 127;
    const float* wr = qw + oc*NC;
    float bias = qb[oc];
    float acc[8];
    #pragma unroll
    for (int i = 0; i < 8; ++i) acc[i] = bias;
    #pragma unroll 4
    for (int c = 0; c < NC; ++c) {
      float w = wr[c];
      #pragma unroll
      for (int i = 0; i < 8; ++i) acc[i] += w * xl[c*16 + half*8 + i];
    }
    int h = oc >> 5, d = oc & 31;
    u16* qp = q + (((size_t)(b*NHH + h))*NN + n0 + half*8)*ND + d;
    #pragma unroll
    for (int i = 0; i < 8; ++i) qp[i*ND] = f2bf(acc[i]*QSCALE);
  } else if (blk < 1024) {
    dwconv_body<7,4,3,16>((blk-512)*256 + t, x, dw1, bn11, pw1, bn12, t1);
  } else if (blk < 3072) {
    dwconv_body<5,2,2,32>((blk-1024)*256 + t, x, dw2, bn21, pw2, bn22, t2);
  } else if (blk < 3328) {
    rpe_body((blk-3072)*256 + t, rpe, rct1, 512, 0);
  } else if (blk < 4352) {
    rpe_body((blk-3328)*256 + t, rpe, rct2, 2048, 1);
  } else {
    // kvw transpose: wt[c][o] = kvw[o][c]   (512x256 -> 256x512)
    int base = ((blk-4352)*256 + t)*4;
    float4 vv = *(const float4*)(kvw + base);
    int o = base >> 8, c = base & 255;
    wt[(c+0)*512 + o] = vv.x;
    wt[(c+1)*512 + o] = vv.y;
    wt[(c+2)*512 + o] = vv.z;
    wt[(c+3)*512 + o] = vv.w;
  }
}

// ---------- stage 2: local 3x3 dw + bias + residual (both branches) ----------
template<int OH>
__device__ __forceinline__ void local_body(int idx, const float* __restrict__ tin,
    const float* __restrict__ lw, const float* __restrict__ lb, float* __restrict__ yout) {
  const int hw = OH*OH;
  int s = idx % hw; int c = (idx/hw) % NC; int b = idx/(hw*NC);
  int oy = s/OH, ox = s%OH;
  const float* tp = tin + (b*NC + c)*hw;
  const float* wp = lw + c*9;
  float acc = lb[c];
  #pragma unroll
  for (int ky = 0; ky < 3; ++ky) {
    int iy = oy - 1 + ky;
    if (iy < 0 || iy >= OH) continue;
    #pragma unroll
    for (int kx = 0; kx < 3; ++kx) {
      int ix = ox - 1 + kx;
      if (ix < 0 || ix >= OH) continue;
      acc += tp[iy*OH + ix]*wp[ky*3 + kx];
    }
  }
  yout[idx] = acc + tp[s];
}

__global__ void __launch_bounds__(256) local_kernel(
    const float* __restrict__ t1, const float* __restrict__ t2,
    const float* __restrict__ lw, const float* __restrict__ lb,
    float* __restrict__ y1, float* __restrict__ y2) {
  int blk = blockIdx.x, t = threadIdx.x;
  if (blk < 512) local_body<16>(blk*256 + t, t1, lw, lb, y1);
  else           local_body<32>((blk-512)*256 + t, t2, lw, lb, y2);
}

// ---------- stage 3: kv 1x1 conv (transposed weights), both branches ----------
__global__ void __launch_bounds__(256) kv_kernel(
    const float* __restrict__ y1, const float* __restrict__ y2,
    const float* __restrict__ wt, const float* __restrict__ kvb,
    u16* __restrict__ kt1, u16* __restrict__ vt1,
    u16* __restrict__ kt2, u16* __restrict__ vt2) {
  __shared__ float yl[NC*4];
  int blk = blockIdx.x, t = threadIdx.x;
  const float* y; u16 *kT, *vT; int hw, b, s0;
  if (blk < 128) { y = y1; kT = kt1; vT = vt1; hw = 256;  b = blk >> 6;  s0 = (blk & 63)*4; }
  else { int v = blk-128; y = y2; kT = kt2; vT = vt2; hw = 1024; b = v >> 8; s0 = (v & 255)*4; }
  #pragma unroll
  for (int j = 0; j < 4; ++j) {
    int idx = t + 256*j;
    int c = idx >> 2, i = idx & 3;
    yl[idx] = y[(b*NC + c)*hw + s0 + i];
  }
  __syncthreads();
  int L = 2*hw;
  for (int half = 0; half < 2; ++half) {
    int o = t + half*256;
    const float* wr = wt + o;        // column o of kvw^T, stride 512
    float bias = kvb[o];
    float acc[4];
    #pragma unroll
    for (int i = 0; i < 4; ++i) acc[i] = bias;
    #pragma unroll 4
    for (int c = 0; c < NC; ++c) {
      float w = wr[c*512];
      #pragma unroll
      for (int i = 0; i < 4; ++i) acc[i] += w*yl[c*4 + i];
    }
    int oc = o & 255;
    int hh2 = oc >> 6, r = oc & 63, d = r >> 1, e = r & 1;
    if (half == 0) {
      u16* kp = kT + ((size_t)((b*NHH + hh2)*L + e*hw + s0))*ND + d;
      #pragma unroll
      for (int i = 0; i < 4; ++i) kp[i*ND] = f2bf(acc[i]);
    } else {
      u16* vp = vT + ((size_t)((b*NHH + hh2)*ND + d))*L + e*hw + s0;
      #pragma unroll
      for (int i = 0; i < 4; ++i) vp[i] = f2bf(acc[i]);
    }
  }
}

// ---------- stage 4: MFMA flash attention, max-free softmax ----------
// blocks [0,512): branch1 full L=512, direct write.
// blocks [512,2560): branch2, one of 4 L-chunks; writes bf16 partial O + ssum.
__global__ void __launch_bounds__(256) attn_kernel(
    const u16* __restrict__ qbf,
    const u16* __restrict__ kt1, const u16* __restrict__ vt1, const u16* __restrict__ rct1,
    const u16* __restrict__ kt2, const u16* __restrict__ vt2, const u16* __restrict__ rct2,
    u32* __restrict__ po32, float* __restrict__ ps,
    float* __restrict__ out) {
  __shared__ u32 pbuf_all[4][16*36];   // per-wave P^T tile, u16-stride 72
  int u = blockIdx.x;
  int br, b, hh, rb, chunk;
  if (u < 512) { br = 0; b = u >> 8; hh = (u >> 6) & 3; rb = u & 63; chunk = 0; }
  else { int v = u - 512; br = 1; chunk = v & 3; rb = (v >> 2) & 63; hh = (v >> 8) & 3; b = v >> 10; }
  int L = br ? 2048 : 512;
  const u16* kT  = br ? kt2 : kt1;
  const u16* vT  = br ? vt2 : vt1;
  const u16* rcT = br ? rct2 : rct1;
  int l0base = chunk * 512;
  int tid = threadIdx.x;
  int w = tid >> 6, lane = tid & 63;
  int g = lane >> 4, lo = lane & 15;
  u32* pbuf = pbuf_all[w];
  u16* pbuf16 = (u16*)pbuf;
  int n = rb*64 + w*16 + lo;

  const u16* kbase = kT + (size_t)(b*NHH + hh)*L*ND;
  const u16* vbase = vT + (size_t)(b*NHH + hh)*ND*L;
  const u16* rcTb  = rcT + (size_t)b*L*80;

  // Q B-frag (pre-scaled by 1/sqrt(32)*log2e)
  short8 qf = *(const short8*)(qbf + (((size_t)(b*NHH + hh))*NN + n)*ND + 8*g);

  // tap-weight B-frag for RPE ext-MFMA
  float fr = ((float)n + 0.5f)*(1.f/64.f) - 0.5f;
  int ri0 = (int)floorf(fr) - 1;
  int a = (w < 2) ? rb - 2 : rb - 1;     // wave-uniform floor(fr(q0)) - 1
  int rmin = a & ~3;
  float wr4[4]; float wsum = 0.f;
  #pragma unroll
  for (int j = 0; j < 4; ++j) {
    int i = ri0 + j;
    float wv = (i >= 0 && i < 64) ? keysw(fr - (float)i) : 0.f;
    wr4[j] = wv; wsum += wv;
  }
  float invw = LOG2E / wsum;
  float wt8[8];
  #pragma unroll
  for (int s = 0; s < 8; ++s) {
    float acc = 0.f;
    #pragma unroll
    for (int j = 0; j < 4; ++j)
      acc += (ri0 + j - rmin == s) ? wr4[j]*invw : 0.f;
    wt8[s] = acc;
  }
  short8 wtf;
  {
    u32 p0 = pk_bf16(wt8[0], wt8[1]), p1 = pk_bf16(wt8[2], wt8[3]);
    u32 p2 = pk_bf16(wt8[4], wt8[5]), p3 = pk_bf16(wt8[6], wt8[7]);
    uint4 uu = make_uint4(p0, p1, p2, p3);
    wtf = __builtin_bit_cast(short8, uu);
    if (g != 0) wtf = (short8)0;
  }
  const u16* rcrow0 = rcTb + (rmin + 4);

  const f32x4 zero = {0.f, 0.f, 0.f, 0.f};
  float ssum = 0.f;
  f32x4 o0 = zero, o1 = zero;

  for (int lt = 0; lt < 8; ++lt) {
    int l0 = l0base + lt*64;
    f32x4 s4[4];
    #pragma unroll
    for (int c = 0; c < 4; ++c) {
      const u16* arow = rcrow0 + (size_t)(l0 + 16*c + lo)*80;
      uint2 ra = *(const uint2*)arow;
      uint2 rb2 = *(const uint2*)(arow + 4);
      uint4 uu = make_uint4(ra.x, ra.y, rb2.x, rb2.y);
      short8 rcf = __builtin_bit_cast(short8, uu);
      f32x4 accr = __builtin_amdgcn_mfma_f32_16x16x32_bf16(rcf, wtf, zero, 0, 0, 0);
      short8 kf = *(const short8*)(kbase + (size_t)(l0 + 16*c + lo)*ND + 8*g);
      s4[c] = __builtin_amdgcn_mfma_f32_16x16x32_bf16(kf, qf, accr, 0, 0, 0);
    }
    // ---- max-free softmax: p = exp2(s) directly (scores bounded ~|10|) ----
    float psum = 0.f;
    u32 pk[8];
    #pragma unroll
    for (int c = 0; c < 4; ++c) {
      float p0 = exp2f(s4[c][0]), p1 = exp2f(s4[c][1]);
      float p2 = exp2f(s4[c][2]), p3 = exp2f(s4[c][3]);
      psum += (p0 + p1) + (p2 + p3);
      pk[2*c]   = pk_bf16(p0, p1);
      pk[2*c+1] = pk_bf16(p2, p3);
    }
    ssum += psum;
    #pragma unroll
    for (int c = 0; c < 4; ++c)
      *(uint2*)(pbuf + lo*36 + 8*c + 2*g) = make_uint2(pk[2*c], pk[2*c+1]);
    #pragma unroll
    for (int kc = 0; kc < 2; ++kc) {
      short8 pf  = *(const short8*)(pbuf16 + lo*72 + 32*kc + 8*g);
      short8 vf0 = *(const short8*)(vbase + (size_t)(lo)*L      + l0 + 32*kc + 8*g);
      short8 vf1 = *(const short8*)(vbase + (size_t)(16 + lo)*L + l0 + 32*kc + 8*g);
      o0 = __builtin_amdgcn_mfma_f32_16x16x32_bf16(vf0, pf, o0, 0, 0, 0);
      o1 = __builtin_amdgcn_mfma_f32_16x16x32_bf16(vf1, pf, o1, 0, 0, 0);
    }
  }
  ssum += __shfl_xor(ssum, 16, 64);
  ssum += __shfl_xor(ssum, 32, 64);
  if (br == 0) {
    float inv = 1.f/ssum;
    f32x4 w0 = o0*inv, w1 = o1*inv;
    float* op = out + ((size_t)((b*NC + hh*64 + rb)*64 + (w*16 + lo)))*64;
    *(f32x4*)(op + 4*g)      = w0;
    *(f32x4*)(op + 16 + 4*g) = w1;
  } else {
    int bh = b*NHH + hh;
    u32* pop = po32 + ((size_t)(bh*NN + n))*64 + chunk*16;
    pop[2*g]     = pk_bf16(o0[0], o0[1]);
    pop[2*g + 1] = pk_bf16(o0[2], o0[3]);
    pop[8 + 2*g]     = pk_bf16(o1[0], o1[1]);
    pop[8 + 2*g + 1] = pk_bf16(o1[2], o1[3]);
    if (g == 0) ps[((size_t)(bh*NN + n))*4 + chunk] = ssum;
  }
}

// ---------- stage 5: combine branch-2 chunk partials (linear) ----------
__global__ void __launch_bounds__(256) combine_kernel(
    const u32* __restrict__ po32, const float* __restrict__ ps,
    float* __restrict__ out) {
  int row = blockIdx.x*256 + threadIdx.x;   // 0..32767 = bh*4096 + n
  float4 sv = *(const float4*)(ps + (size_t)row*4);
  float inv = 1.f/((sv.x + sv.y) + (sv.z + sv.w));
  const u32* pp = po32 + (size_t)row*64;
  float o[32];
  #pragma unroll
  for (int j = 0; j < 16; ++j) {
    u32 a0 = pp[j], a1 = pp[16+j], a2 = pp[32+j], a3 = pp[48+j];
    float lo0 = __uint_as_float(a0 << 16),        lo1 = __uint_as_float(a1 << 16);
    float lo2 = __uint_as_float(a2 << 16),        lo3 = __uint_as_float(a3 << 16);
    float hi0 = __uint_as_float(a0 & 0xffff0000u), hi1 = __uint_as_float(a1 & 0xffff0000u);
    float hi2 = __uint_as_float(a2 & 0xffff0000u), hi3 = __uint_as_float(a3 & 0xffff0000u);
    o[2*j]   = ((lo0 + lo1) + (lo2 + lo3))*inv;
    o[2*j+1] = ((hi0 + hi1) + (hi2 + hi3))*inv;
  }
  int bh = row >> 12, n = row & 4095;
  float* op = out + ((size_t)(((bh>>2)*NC + (bh&3)*64 + (n>>6))*64 + (n&63)))*64 + 32;
  #pragma unroll
  for (int j = 0; j < 8; ++j) {
    f32x4 v = {o[4*j], o[4*j+1], o[4*j+2], o[4*j+3]};
    *(f32x4*)(op + 4*j) = v;
  }
}

extern "C" void kernel_launch(void* const* d_in, const int* in_sizes, int n_in,
                              void* d_out, int out_size, void* d_ws, size_t ws_size,
                              hipStream_t stream) {
  const float* x    = (const float*)d_in[0];
  const float* rpe  = (const float*)d_in[1];
  const float* qw   = (const float*)d_in[2];
  const float* qb   = (const float*)d_in[3];
  const float* kvw  = (const float*)d_in[4];
  const float* kvb  = (const float*)d_in[5];
  const float* dw1  = (const float*)d_in[6];
  const float* bn11 = (const float*)d_in[7];
  const float* pw1  = (const float*)d_in[8];
  const float* bn12 = (const float*)d_in[9];
  const float* dw2  = (const float*)d_in[10];
  const float* bn21 = (const float*)d_in[11];
  const float* pw2  = (const float*)d_in[12];
  const float* bn22 = (const float*)d_in[13];
  const float* lw   = (const float*)d_in[14];
  const float* lb   = (const float*)d_in[15];
  float* out = (float*)d_out;
  float* ws  = (float*)d_ws;

  float* t1   = ws + OFF_T1;
  float* y1   = ws + OFF_Y1;
  float* t2   = ws + OFF_T2;
  float* y2   = ws + OFF_Y2;
  u16*   q    = (u16*)(ws + OFF_Q);
  u16*   kt1  = (u16*)(ws + OFF_KT1);
  u16*   vt1  = (u16*)(ws + OFF_VT1);
  u16*   kt2  = (u16*)(ws + OFF_KT2);
  u16*   vt2  = (u16*)(ws + OFF_VT2);
  u16*   rct1 = (u16*)(ws + OFF_RCT1);
  u16*   rct2 = (u16*)(ws + OFF_RCT2);
  float* wt   = ws + OFF_WT;
  u32*   po32 = (u32*)(ws + OFF_PO);
  float* ps   = ws + OFF_PS;

  hipLaunchKernelGGL(prep_kernel, dim3(4480), dim3(256), 0, stream,
                     x, qw, qb, q, dw1, bn11, pw1, bn12, t1,
                     dw2, bn21, pw2, bn22, t2, rpe, rct1, rct2, kvw, wt);
  hipLaunchKernelGGL(local_kernel, dim3(2560), dim3(256), 0, stream,
                     t1, t2, lw, lb, y1, y2);
  hipLaunchKernelGGL(kv_kernel, dim3(640), dim3(256), 0, stream,
                     y1, y2, wt, kvb, kt1, vt1, kt2, vt2);
  hipLaunchKernelGGL(attn_kernel, dim3(2560), dim3(256), 0, stream,
                     q, kt1, vt1, rct1, kt2, vt2, rct2, po32, ps, out);
  hipLaunchKernelGGL(combine_kernel, dim3(128), dim3(256), 0, stream,
                     po32, ps, out);
}

// Round 8
// 227.562 us; speedup vs baseline: 1.7594x; 1.1078x over previous
//
#include <hip/hip_runtime.h>
#include <hip/hip_bf16.h>
#include <math.h>

#define NB 2
#define NC 256
#define HWIN 4096
#define NN 4096
#define ND 32
#define NHH 4
#define EPSV 1e-5f

typedef short short8 __attribute__((ext_vector_type(8)));
typedef float f32x4 __attribute__((ext_vector_type(4)));
typedef unsigned short u16;
typedef unsigned int u32;

// workspace offsets (float32 units)
#define OFF_T1   0          // 131072
#define OFF_Y1   131072     // 131072
#define OFF_T2   262144     // 524288
#define OFF_Y2   786432     // 524288
#define OFF_Q    1310720    // 524288 (bf16 x 1048576)
#define OFF_KT1  1835008    // 65536
#define OFF_VT1  1900544    // 65536
#define OFF_KT2  1966080    // 262144
#define OFF_VT2  2228224    // 262144
#define OFF_RCT1 2490368    // 40960
#define OFF_RCT2 2531328    // 163840
#define OFF_WT   2695168    // 131072  (kvw^T, f32 [c][o] 256x512)
#define OFF_PO   2826240    // 2097152 (br2 partial O, u32-packed bf16 pairs)
#define OFF_PS   4923392    // 131072  (br2 partial ssum, [row][4])
#define OFF_QWT  5054464    // 32768   (qw^T, f32 [c][oc] 256x128)
// end 5087232 floats = 20.3 MB

#define QSCALE 0.2550437314857726f   // 1/sqrt(32) * log2(e)
#define LOG2E  1.4426950408889634f

__device__ __forceinline__ u16 f2bf(float x) {   // f32 -> bf16 RNE
  unsigned u = __float_as_uint(x);
  u += 0x7fffu + ((u >> 16) & 1u);
  return (u16)(u >> 16);
}

__device__ __forceinline__ u32 pk_bf16(float a, float b) {  // packed RNE cvt
  __hip_bfloat162 h = __float22bfloat162_rn(make_float2(a, b));
  u32 r; __builtin_memcpy(&r, &h, 4);
  return r;
}

__device__ __forceinline__ float keysw(float t) {  // Keys cubic, a=-0.5
  t = fabsf(t);
  float w;
  if (t < 1.f)       w = ((1.5f*t - 2.5f)*t)*t + 1.f;
  else if (t < 2.f)  w = ((-0.5f*t + 2.5f)*t - 4.f)*t + 2.f;
  else               w = 0.f;
  return w;
}

// ---------- device bodies ----------
template<int KS, int STR, int PAD, int OH>
__device__ __forceinline__ void dwconv_body(int idx, const float* __restrict__ x,
    const float* __restrict__ dww, const float* __restrict__ bn1,
    const float* __restrict__ pww, const float* __restrict__ bn2,
    float* __restrict__ tout) {
  const int hw = OH*OH;
  int s = idx % hw; int c = (idx/hw) % NC; int b = idx/(hw*NC);
  int oy = s / OH, ox = s % OH;
  const float* xp = x + (b*NC + c)*HWIN;
  const float* wp = dww + c*KS*KS;
  float acc = 0.f;
  #pragma unroll
  for (int ky = 0; ky < KS; ++ky) {
    int iy = oy*STR - PAD + ky;
    if (iy < 0 || iy >= 64) continue;
    #pragma unroll
    for (int kx = 0; kx < KS; ++kx) {
      int ix = ox*STR - PAD + kx;
      if (ix < 0 || ix >= 64) continue;
      acc += xp[iy*64 + ix] * wp[ky*KS + kx];
    }
  }
  float s1 = bn1[c] * rsqrtf(bn1[3*NC + c] + EPSV);
  float z = (acc - bn1[2*NC + c])*s1 + bn1[NC + c];
  z = fmaxf(z, 0.f);
  float s2 = bn2[c] * rsqrtf(bn2[3*NC + c] + EPSV);
  z = z * (pww[c]*s2) + (bn2[NC + c] - bn2[2*NC + c]*s2);
  tout[idx] = z;
}

__device__ __forceinline__ void rpe_body(int idx, const float* __restrict__ rpe,
                                         u16* __restrict__ rcT, int L, int ch) {
  int r = idx & 63; int l = (idx >> 6) % L; int b = idx / (64*L);
  float f = ((float)l + 0.5f)*(64.f/(float)L) - 0.5f;
  int i0 = (int)floorf(f) - 1;
  const float* rp = rpe + ((b*2 + ch)*64 + r)*64;
  float v = 0.f, wsum = 0.f;
  #pragma unroll
  for (int j = 0; j < 4; ++j) {
    int i = i0 + j;
    if (i >= 0 && i < 64) {
      float w = keysw(f - (float)i);
      v += w * rp[i]; wsum += w;
    }
  }
  rcT[((size_t)(b*L + l))*80 + 4 + r] = f2bf(v / wsum);
}

// ---------- stage 1: dwconv1 + dwconv2 + rpe1 + rpe2 + kvw^T + qw^T ----------
__global__ void __launch_bounds__(256) prep_kernel(
    const float* __restrict__ x,
    const float* __restrict__ dw1, const float* __restrict__ bn11,
    const float* __restrict__ pw1, const float* __restrict__ bn12, float* __restrict__ t1,
    const float* __restrict__ dw2, const float* __restrict__ bn21,
    const float* __restrict__ pw2, const float* __restrict__ bn22, float* __restrict__ t2,
    const float* __restrict__ rpe, u16* __restrict__ rct1, u16* __restrict__ rct2,
    const float* __restrict__ kvw, float* __restrict__ wt,
    const float* __restrict__ qw, float* __restrict__ qwt) {
  int blk = blockIdx.x;
  int t = threadIdx.x;
  if (blk < 512) {
    dwconv_body<7,4,3,16>(blk*256 + t, x, dw1, bn11, pw1, bn12, t1);
  } else if (blk < 2560) {
    dwconv_body<5,2,2,32>((blk-512)*256 + t, x, dw2, bn21, pw2, bn22, t2);
  } else if (blk < 2816) {
    rpe_body((blk-2560)*256 + t, rpe, rct1, 512, 0);
  } else if (blk < 3840) {
    rpe_body((blk-2816)*256 + t, rpe, rct2, 2048, 1);
  } else if (blk < 3968) {
    // kvw transpose: wt[c][o] = kvw[o][c]   (512x256 -> 256x512)
    int base = ((blk-3840)*256 + t)*4;
    float4 vv = *(const float4*)(kvw + base);
    int o = base >> 8, c = base & 255;
    wt[(c+0)*512 + o] = vv.x;
    wt[(c+1)*512 + o] = vv.y;
    wt[(c+2)*512 + o] = vv.z;
    wt[(c+3)*512 + o] = vv.w;
  } else {
    // qw transpose: qwt[c][oc] = qw[oc][c]  (128x256 -> 256x128)
    int base = ((blk-3968)*256 + t)*4;
    float4 vv = *(const float4*)(qw + base);
    int oc = base >> 8, c = base & 255;
    qwt[(c+0)*128 + oc] = vv.x;
    qwt[(c+1)*128 + oc] = vv.y;
    qwt[(c+2)*128 + oc] = vv.z;
    qwt[(c+3)*128 + oc] = vv.w;
  }
}

// ---------- stage 2: local 3x3 dw + bias + residual (both branches) ----------
template<int OH>
__device__ __forceinline__ void local_body(int idx, const float* __restrict__ tin,
    const float* __restrict__ lw, const float* __restrict__ lb, float* __restrict__ yout) {
  const int hw = OH*OH;
  int s = idx % hw; int c = (idx/hw) % NC; int b = idx/(hw*NC);
  int oy = s/OH, ox = s%OH;
  const float* tp = tin + (b*NC + c)*hw;
  const float* wp = lw + c*9;
  float acc = lb[c];
  #pragma unroll
  for (int ky = 0; ky < 3; ++ky) {
    int iy = oy - 1 + ky;
    if (iy < 0 || iy >= OH) continue;
    #pragma unroll
    for (int kx = 0; kx < 3; ++kx) {
      int ix = ox - 1 + kx;
      if (ix < 0 || ix >= OH) continue;
      acc += tp[iy*OH + ix]*wp[ky*3 + kx];
    }
  }
  yout[idx] = acc + tp[s];
}

__global__ void __launch_bounds__(256) local_kernel(
    const float* __restrict__ t1, const float* __restrict__ t2,
    const float* __restrict__ lw, const float* __restrict__ lb,
    float* __restrict__ y1, float* __restrict__ y2) {
  int blk = blockIdx.x, t = threadIdx.x;
  if (blk < 512) local_body<16>(blk*256 + t, t1, lw, lb, y1);
  else           local_body<32>((blk-512)*256 + t, t2, lw, lb, y2);
}

// ---------- stage 3: kv 1x1 conv (both branches) + q 1x1 conv ----------
__global__ void __launch_bounds__(256) kv_kernel(
    const float* __restrict__ y1, const float* __restrict__ y2,
    const float* __restrict__ wt, const float* __restrict__ kvb,
    u16* __restrict__ kt1, u16* __restrict__ vt1,
    u16* __restrict__ kt2, u16* __restrict__ vt2,
    const float* __restrict__ x, const float* __restrict__ qwt,
    const float* __restrict__ qb, u16* __restrict__ q) {
  __shared__ float sbuf[NC*16];
  int blk = blockIdx.x, t = threadIdx.x;
  if (blk < 640) {
    // ---- kv conv ----
    const float* y; u16 *kT, *vT; int hw, b, s0;
    if (blk < 128) { y = y1; kT = kt1; vT = vt1; hw = 256;  b = blk >> 6;  s0 = (blk & 63)*4; }
    else { int v = blk-128; y = y2; kT = kt2; vT = vt2; hw = 1024; b = v >> 8; s0 = (v & 255)*4; }
    #pragma unroll
    for (int j = 0; j < 4; ++j) {
      int idx = t + 256*j;
      int c = idx >> 2, i = idx & 3;
      sbuf[idx] = y[(b*NC + c)*hw + s0 + i];
    }
    __syncthreads();
    int L = 2*hw;
    for (int half = 0; half < 2; ++half) {
      int o = t + half*256;
      const float* wr = wt + o;        // column o of kvw^T, stride 512
      float bias = kvb[o];
      float acc[4];
      #pragma unroll
      for (int i = 0; i < 4; ++i) acc[i] = bias;
      #pragma unroll 4
      for (int c = 0; c < NC; ++c) {
        float w = wr[c*512];
        #pragma unroll
        for (int i = 0; i < 4; ++i) acc[i] += w*sbuf[c*4 + i];
      }
      int oc = o & 255;
      int hh2 = oc >> 6, r = oc & 63, d = r >> 1, e = r & 1;
      if (half == 0) {
        u16* kp = kT + ((size_t)((b*NHH + hh2)*L + e*hw + s0))*ND + d;
        #pragma unroll
        for (int i = 0; i < 4; ++i) kp[i*ND] = f2bf(acc[i]);
      } else {
        u16* vp = vT + ((size_t)((b*NHH + hh2)*ND + d))*L + e*hw + s0;
        #pragma unroll
        for (int i = 0; i < 4; ++i) vp[i] = f2bf(acc[i]);
      }
    }
  } else {
    // ---- q conv: 16 spatial/block, coalesced qwt weights ----
    int blk2 = blk - 640;           // 0..511
    int b = blk2 >> 8;
    int n0 = (blk2 & 255) * 16;
    #pragma unroll
    for (int j = 0; j < 16; ++j) {
      int idx = t + 256*j;
      int c = idx >> 4, i = idx & 15;
      sbuf[idx] = x[(b*NC + c)*HWIN + n0 + i];
    }
    __syncthreads();
    int half = t >> 7, oc = t & 127;
    float bias = qb[oc];
    float acc[8];
    #pragma unroll
    for (int i = 0; i < 8; ++i) acc[i] = bias;
    #pragma unroll 4
    for (int c = 0; c < NC; ++c) {
      float w = qwt[c*128 + oc];     // coalesced across lanes
      #pragma unroll
      for (int i = 0; i < 8; ++i) acc[i] += w * sbuf[c*16 + half*8 + i];
    }
    int h = oc >> 5, d = oc & 31;
    u16* qp = q + (((size_t)(b*NHH + h))*NN + n0 + half*8)*ND + d;
    #pragma unroll
    for (int i = 0; i < 8; ++i) qp[i*ND] = f2bf(acc[i]*QSCALE);
  }
}

// ---------- stage 4: MFMA flash attention, max-free softmax, prefetched ----------
// blocks [0,512): branch1 full L=512, direct write.
// blocks [512,2560): branch2, one of 4 L-chunks; writes bf16 partial O + ssum.
__global__ void __launch_bounds__(256) attn_kernel(
    const u16* __restrict__ qbf,
    const u16* __restrict__ kt1, const u16* __restrict__ vt1, const u16* __restrict__ rct1,
    const u16* __restrict__ kt2, const u16* __restrict__ vt2, const u16* __restrict__ rct2,
    u32* __restrict__ po32, float* __restrict__ ps,
    float* __restrict__ out) {
  __shared__ u32 pbuf_all[4][16*36];   // per-wave P^T tile, u16-stride 72
  int u = blockIdx.x;
  int br, b, hh, rb, chunk;
  if (u < 512) { br = 0; b = u >> 8; hh = (u >> 6) & 3; rb = u & 63; chunk = 0; }
  else { int v = u - 512; br = 1; chunk = v & 3; rb = (v >> 2) & 63; hh = (v >> 8) & 3; b = v >> 10; }
  int L = br ? 2048 : 512;
  const u16* kT  = br ? kt2 : kt1;
  const u16* vT  = br ? vt2 : vt1;
  const u16* rcT = br ? rct2 : rct1;
  int l0base = chunk * 512;
  int tid = threadIdx.x;
  int w = tid >> 6, lane = tid & 63;
  int g = lane >> 4, lo = lane & 15;
  u32* pbuf = pbuf_all[w];
  u16* pbuf16 = (u16*)pbuf;
  int n = rb*64 + w*16 + lo;

  const u16* kbase = kT + (size_t)(b*NHH + hh)*L*ND;
  const u16* vbase = vT + (size_t)(b*NHH + hh)*ND*L;
  const u16* rcTb  = rcT + (size_t)b*L*80;

  // Q B-frag (pre-scaled by 1/sqrt(32)*log2e)
  short8 qf = *(const short8*)(qbf + (((size_t)(b*NHH + hh))*NN + n)*ND + 8*g);

  // tap-weight B-frag for RPE ext-MFMA
  float fr = ((float)n + 0.5f)*(1.f/64.f) - 0.5f;
  int ri0 = (int)floorf(fr) - 1;
  int a = (w < 2) ? rb - 2 : rb - 1;     // wave-uniform floor(fr(q0)) - 1
  int rmin = a & ~3;
  float wr4[4]; float wsum = 0.f;
  #pragma unroll
  for (int j = 0; j < 4; ++j) {
    int i = ri0 + j;
    float wv = (i >= 0 && i < 64) ? keysw(fr - (float)i) : 0.f;
    wr4[j] = wv; wsum += wv;
  }
  float invw = LOG2E / wsum;
  float wt8[8];
  #pragma unroll
  for (int s = 0; s < 8; ++s) {
    float acc = 0.f;
    #pragma unroll
    for (int j = 0; j < 4; ++j)
      acc += (ri0 + j - rmin == s) ? wr4[j]*invw : 0.f;
    wt8[s] = acc;
  }
  short8 wtf;
  {
    u32 p0 = pk_bf16(wt8[0], wt8[1]), p1 = pk_bf16(wt8[2], wt8[3]);
    u32 p2 = pk_bf16(wt8[4], wt8[5]), p3 = pk_bf16(wt8[6], wt8[7]);
    uint4 uu = make_uint4(p0, p1, p2, p3);
    wtf = __builtin_bit_cast(short8, uu);
    if (g != 0) wtf = (short8)0;
  }
  const u16* rcrow0 = rcTb + (rmin + 4);

  const f32x4 zero = {0.f, 0.f, 0.f, 0.f};
  float ssum = 0.f;
  f32x4 o0 = zero, o1 = zero;

  // ---- prefetch helpers (K-frags + rc-frags one tile ahead) ----
  auto loadKR = [&](short8 (&kf)[4], uint4 (&rc)[4], int l0) {
    #pragma unroll
    for (int c = 0; c < 4; ++c) {
      const u16* arow = rcrow0 + (size_t)(l0 + 16*c + lo)*80;
      uint2 ra = *(const uint2*)arow;
      uint2 rb2 = *(const uint2*)(arow + 4);
      rc[c] = make_uint4(ra.x, ra.y, rb2.x, rb2.y);
      kf[c] = *(const short8*)(kbase + (size_t)(l0 + 16*c + lo)*ND + 8*g);
    }
  };
  auto proc = [&](short8 (&kf)[4], uint4 (&rc)[4], int l0) {
    // V loads issued first: consumed only after softmax+LDS (natural slack)
    short8 v00 = *(const short8*)(vbase + (size_t)lo*L      + l0 + 8*g);
    short8 v01 = *(const short8*)(vbase + (size_t)lo*L      + l0 + 32 + 8*g);
    short8 v10 = *(const short8*)(vbase + (size_t)(16+lo)*L + l0 + 8*g);
    short8 v11 = *(const short8*)(vbase + (size_t)(16+lo)*L + l0 + 32 + 8*g);
    f32x4 s4[4];
    #pragma unroll
    for (int c = 0; c < 4; ++c) {
      short8 rcf = __builtin_bit_cast(short8, rc[c]);
      f32x4 accr = __builtin_amdgcn_mfma_f32_16x16x32_bf16(rcf, wtf, zero, 0, 0, 0);
      s4[c] = __builtin_amdgcn_mfma_f32_16x16x32_bf16(kf[c], qf, accr, 0, 0, 0);
    }
    float psum = 0.f;
    u32 pk[8];
    #pragma unroll
    for (int c = 0; c < 4; ++c) {
      float p0 = exp2f(s4[c][0]), p1 = exp2f(s4[c][1]);
      float p2 = exp2f(s4[c][2]), p3 = exp2f(s4[c][3]);
      psum += (p0 + p1) + (p2 + p3);
      pk[2*c]   = pk_bf16(p0, p1);
      pk[2*c+1] = pk_bf16(p2, p3);
    }
    ssum += psum;
    #pragma unroll
    for (int c = 0; c < 4; ++c)
      *(uint2*)(pbuf + lo*36 + 8*c + 2*g) = make_uint2(pk[2*c], pk[2*c+1]);
    short8 pf0 = *(const short8*)(pbuf16 + lo*72 + 8*g);
    short8 pf1 = *(const short8*)(pbuf16 + lo*72 + 32 + 8*g);
    o0 = __builtin_amdgcn_mfma_f32_16x16x32_bf16(v00, pf0, o0, 0, 0, 0);
    o1 = __builtin_amdgcn_mfma_f32_16x16x32_bf16(v10, pf0, o1, 0, 0, 0);
    o0 = __builtin_amdgcn_mfma_f32_16x16x32_bf16(v01, pf1, o0, 0, 0, 0);
    o1 = __builtin_amdgcn_mfma_f32_16x16x32_bf16(v11, pf1, o1, 0, 0, 0);
  };

  short8 kfa[4], kfb[4]; uint4 rca[4], rcb[4];
  loadKR(kfa, rca, l0base);
  #pragma unroll
  for (int p = 0; p < 4; ++p) {
    int l0 = l0base + p*128;
    loadKR(kfb, rcb, l0 + 64);
    proc(kfa, rca, l0);
    if (p < 3) loadKR(kfa, rca, l0 + 128);
    proc(kfb, rcb, l0 + 64);
  }

  ssum += __shfl_xor(ssum, 16, 64);
  ssum += __shfl_xor(ssum, 32, 64);
  if (br == 0) {
    float inv = 1.f/ssum;
    f32x4 w0 = o0*inv, w1 = o1*inv;
    float* op = out + ((size_t)((b*NC + hh*64 + rb)*64 + (w*16 + lo)))*64;
    *(f32x4*)(op + 4*g)      = w0;
    *(f32x4*)(op + 16 + 4*g) = w1;
  } else {
    int bh = b*NHH + hh;
    u32* pop = po32 + ((size_t)(bh*NN + n))*64 + chunk*16;
    pop[2*g]     = pk_bf16(o0[0], o0[1]);
    pop[2*g + 1] = pk_bf16(o0[2], o0[3]);
    pop[8 + 2*g]     = pk_bf16(o1[0], o1[1]);
    pop[8 + 2*g + 1] = pk_bf16(o1[2], o1[3]);
    if (g == 0) ps[((size_t)(bh*NN + n))*4 + chunk] = ssum;
  }
}

// ---------- stage 5: combine branch-2 chunk partials (linear) ----------
__global__ void __launch_bounds__(256) combine_kernel(
    const u32* __restrict__ po32, const float* __restrict__ ps,
    float* __restrict__ out) {
  int row = blockIdx.x*256 + threadIdx.x;   // 0..32767 = bh*4096 + n
  float4 sv = *(const float4*)(ps + (size_t)row*4);
  float inv = 1.f/((sv.x + sv.y) + (sv.z + sv.w));
  const u32* pp = po32 + (size_t)row*64;
  float o[32];
  #pragma unroll
  for (int j = 0; j < 16; ++j) {
    u32 a0 = pp[j], a1 = pp[16+j], a2 = pp[32+j], a3 = pp[48+j];
    float lo0 = __uint_as_float(a0 << 16),        lo1 = __uint_as_float(a1 << 16);
    float lo2 = __uint_as_float(a2 << 16),        lo3 = __uint_as_float(a3 << 16);
    float hi0 = __uint_as_float(a0 & 0xffff0000u), hi1 = __uint_as_float(a1 & 0xffff0000u);
    float hi2 = __uint_as_float(a2 & 0xffff0000u), hi3 = __uint_as_float(a3 & 0xffff0000u);
    o[2*j]   = ((lo0 + lo1) + (lo2 + lo3))*inv;
    o[2*j+1] = ((hi0 + hi1) + (hi2 + hi3))*inv;
  }
  int bh = row >> 12, n = row & 4095;
  float* op = out + ((size_t)(((bh>>2)*NC + (bh&3)*64 + (n>>6))*64 + (n&63)))*64 + 32;
  #pragma unroll
  for (int j = 0; j < 8; ++j) {
    f32x4 v = {o[4*j], o[4*j+1], o[4*j+2], o[4*j+3]};
    *(f32x4*)(op + 4*j) = v;
  }
}

extern "C" void kernel_launch(void* const* d_in, const int* in_sizes, int n_in,
                              void* d_out, int out_size, void* d_ws, size_t ws_size,
                              hipStream_t stream) {
  const float* x    = (const float*)d_in[0];
  const float* rpe  = (const float*)d_in[1];
  const float* qw   = (const float*)d_in[2];
  const float* qb   = (const float*)d_in[3];
  const float* kvw  = (const float*)d_in[4];
  const float* kvb  = (const float*)d_in[5];
  const float* dw1  = (const float*)d_in[6];
  const float* bn11 = (const float*)d_in[7];
  const float* pw1  = (const float*)d_in[8];
  const float* bn12 = (const float*)d_in[9];
  const float* dw2  = (const float*)d_in[10];
  const float* bn21 = (const float*)d_in[11];
  const float* pw2  = (const float*)d_in[12];
  const float* bn22 = (const float*)d_in[13];
  const float* lw   = (const float*)d_in[14];
  const float* lb   = (const float*)d_in[15];
  float* out = (float*)d_out;
  float* ws  = (float*)d_ws;

  float* t1   = ws + OFF_T1;
  float* y1   = ws + OFF_Y1;
  float* t2   = ws + OFF_T2;
  float* y2   = ws + OFF_Y2;
  u16*   q    = (u16*)(ws + OFF_Q);
  u16*   kt1  = (u16*)(ws + OFF_KT1);
  u16*   vt1  = (u16*)(ws + OFF_VT1);
  u16*   kt2  = (u16*)(ws + OFF_KT2);
  u16*   vt2  = (u16*)(ws + OFF_VT2);
  u16*   rct1 = (u16*)(ws + OFF_RCT1);
  u16*   rct2 = (u16*)(ws + OFF_RCT2);
  float* wt   = ws + OFF_WT;
  u32*   po32 = (u32*)(ws + OFF_PO);
  float* ps   = ws + OFF_PS;
  float* qwt  = ws + OFF_QWT;

  hipLaunchKernelGGL(prep_kernel, dim3(4000), dim3(256), 0, stream,
                     x, dw1, bn11, pw1, bn12, t1, dw2, bn21, pw2, bn22, t2,
                     rpe, rct1, rct2, kvw, wt, qw, qwt);
  hipLaunchKernelGGL(local_kernel, dim3(2560), dim3(256), 0, stream,
                     t1, t2, lw, lb, y1, y2);
  hipLaunchKernelGGL(kv_kernel, dim3(1152), dim3(256), 0, stream,
                     y1, y2, wt, kvb, kt1, vt1, kt2, vt2, x, qwt, qb, q);
  hipLaunchKernelGGL(attn_kernel, dim3(2560), dim3(256), 0, stream,
                     q, kt1, vt1, rct1, kt2, vt2, rct2, po32, ps, out);
  hipLaunchKernelGGL(combine_kernel, dim3(128), dim3(256), 0, stream,
                     po32, ps, out);
}

// Round 9
// 195.562 us; speedup vs baseline: 2.0472x; 1.1636x over previous
//
#include <hip/hip_runtime.h>
#include <hip/hip_bf16.h>
#include <math.h>

#define NB 2
#define NC 256
#define HWIN 4096
#define NN 4096
#define ND 32
#define NHH 4
#define EPSV 1e-5f

typedef short short8 __attribute__((ext_vector_type(8)));
typedef float f32x4 __attribute__((ext_vector_type(4)));
typedef unsigned short u16;
typedef unsigned int u32;

// workspace offsets (float32 units)
#define OFF_T1   0          // 131072
#define OFF_Y1   131072     // 131072
#define OFF_T2   262144     // 524288
#define OFF_Y2   786432     // 524288
#define OFF_Q    1310720    // 524288 (bf16 x 1048576)
#define OFF_KT1  1835008    // 65536
#define OFF_VT1  1900544    // 65536
#define OFF_KT2  1966080    // 262144
#define OFF_VT2  2228224    // 262144
#define OFF_RCT1 2490368    // 40960
#define OFF_RCT2 2531328    // 163840
#define OFF_WT   2695168    // 131072  (kvw^T, f32 [c][o] 256x512)
#define OFF_PO   2826240    // 2097152 u32: po[chunk][32768 rows][16]
#define OFF_PS   4923392    // 131072: ps[chunk][32768 rows]
#define OFF_QWT  5054464    // 32768   (qw^T, f32 [c][oc] 256x128)
// end 5087232 floats = 20.3 MB

#define QSCALE 0.2550437314857726f   // 1/sqrt(32) * log2(e)
#define LOG2E  1.4426950408889634f

__device__ __forceinline__ u16 f2bf(float x) {   // f32 -> bf16 RNE
  unsigned u = __float_as_uint(x);
  u += 0x7fffu + ((u >> 16) & 1u);
  return (u16)(u >> 16);
}

__device__ __forceinline__ u32 pk_bf16(float a, float b) {  // packed RNE cvt
  __hip_bfloat162 h = __float22bfloat162_rn(make_float2(a, b));
  u32 r; __builtin_memcpy(&r, &h, 4);
  return r;
}

__device__ __forceinline__ float keysw(float t) {  // Keys cubic, a=-0.5
  t = fabsf(t);
  float w;
  if (t < 1.f)       w = ((1.5f*t - 2.5f)*t)*t + 1.f;
  else if (t < 2.f)  w = ((-0.5f*t + 2.5f)*t - 4.f)*t + 2.f;
  else               w = 0.f;
  return w;
}

// ---------- device bodies ----------
template<int KS, int STR, int PAD, int OH>
__device__ __forceinline__ void dwconv_body(int idx, const float* __restrict__ x,
    const float* __restrict__ dww, const float* __restrict__ bn1,
    const float* __restrict__ pww, const float* __restrict__ bn2,
    float* __restrict__ tout) {
  const int hw = OH*OH;
  int s = idx % hw; int c = (idx/hw) % NC; int b = idx/(hw*NC);
  int oy = s / OH, ox = s % OH;
  const float* xp = x + (b*NC + c)*HWIN;
  const float* wp = dww + c*KS*KS;
  float acc = 0.f;
  #pragma unroll
  for (int ky = 0; ky < KS; ++ky) {
    int iy = oy*STR - PAD + ky;
    if (iy < 0 || iy >= 64) continue;
    #pragma unroll
    for (int kx = 0; kx < KS; ++kx) {
      int ix = ox*STR - PAD + kx;
      if (ix < 0 || ix >= 64) continue;
      acc += xp[iy*64 + ix] * wp[ky*KS + kx];
    }
  }
  float s1 = bn1[c] * rsqrtf(bn1[3*NC + c] + EPSV);
  float z = (acc - bn1[2*NC + c])*s1 + bn1[NC + c];
  z = fmaxf(z, 0.f);
  float s2 = bn2[c] * rsqrtf(bn2[3*NC + c] + EPSV);
  z = z * (pww[c]*s2) + (bn2[NC + c] - bn2[2*NC + c]*s2);
  tout[idx] = z;
}

__device__ __forceinline__ void rpe_body(int idx, const float* __restrict__ rpe,
                                         u16* __restrict__ rcT, int L, int ch) {
  int r = idx & 63; int l = (idx >> 6) % L; int b = idx / (64*L);
  float f = ((float)l + 0.5f)*(64.f/(float)L) - 0.5f;
  int i0 = (int)floorf(f) - 1;
  const float* rp = rpe + ((b*2 + ch)*64 + r)*64;
  float v = 0.f, wsum = 0.f;
  #pragma unroll
  for (int j = 0; j < 4; ++j) {
    int i = i0 + j;
    if (i >= 0 && i < 64) {
      float w = keysw(f - (float)i);
      v += w * rp[i]; wsum += w;
    }
  }
  rcT[((size_t)(b*L + l))*80 + 4 + r] = f2bf(v / wsum);
}

// ---------- stage 1: dwconv1 + dwconv2 + rpe1 + rpe2 + kvw^T + qw^T ----------
__global__ void __launch_bounds__(256) prep_kernel(
    const float* __restrict__ x,
    const float* __restrict__ dw1, const float* __restrict__ bn11,
    const float* __restrict__ pw1, const float* __restrict__ bn12, float* __restrict__ t1,
    const float* __restrict__ dw2, const float* __restrict__ bn21,
    const float* __restrict__ pw2, const float* __restrict__ bn22, float* __restrict__ t2,
    const float* __restrict__ rpe, u16* __restrict__ rct1, u16* __restrict__ rct2,
    const float* __restrict__ kvw, float* __restrict__ wt,
    const float* __restrict__ qw, float* __restrict__ qwt) {
  int blk = blockIdx.x;
  int t = threadIdx.x;
  if (blk < 512) {
    dwconv_body<7,4,3,16>(blk*256 + t, x, dw1, bn11, pw1, bn12, t1);
  } else if (blk < 2560) {
    dwconv_body<5,2,2,32>((blk-512)*256 + t, x, dw2, bn21, pw2, bn22, t2);
  } else if (blk < 2816) {
    rpe_body((blk-2560)*256 + t, rpe, rct1, 512, 0);
  } else if (blk < 3840) {
    rpe_body((blk-2816)*256 + t, rpe, rct2, 2048, 1);
  } else if (blk < 3968) {
    // kvw transpose: wt[c][o] = kvw[o][c]   (512x256 -> 256x512)
    int base = ((blk-3840)*256 + t)*4;
    float4 vv = *(const float4*)(kvw + base);
    int o = base >> 8, c = base & 255;
    wt[(c+0)*512 + o] = vv.x;
    wt[(c+1)*512 + o] = vv.y;
    wt[(c+2)*512 + o] = vv.z;
    wt[(c+3)*512 + o] = vv.w;
  } else {
    // qw transpose: qwt[c][oc] = qw[oc][c]  (128x256 -> 256x128)
    int base = ((blk-3968)*256 + t)*4;
    float4 vv = *(const float4*)(qw + base);
    int oc = base >> 8, c = base & 255;
    qwt[(c+0)*128 + oc] = vv.x;
    qwt[(c+1)*128 + oc] = vv.y;
    qwt[(c+2)*128 + oc] = vv.z;
    qwt[(c+3)*128 + oc] = vv.w;
  }
}

// ---------- stage 2: local 3x3 dw + bias + residual (both branches) ----------
template<int OH>
__device__ __forceinline__ void local_body(int idx, const float* __restrict__ tin,
    const float* __restrict__ lw, const float* __restrict__ lb, float* __restrict__ yout) {
  const int hw = OH*OH;
  int s = idx % hw; int c = (idx/hw) % NC; int b = idx/(hw*NC);
  int oy = s/OH, ox = s%OH;
  const float* tp = tin + (b*NC + c)*hw;
  const float* wp = lw + c*9;
  float acc = lb[c];
  #pragma unroll
  for (int ky = 0; ky < 3; ++ky) {
    int iy = oy - 1 + ky;
    if (iy < 0 || iy >= OH) continue;
    #pragma unroll
    for (int kx = 0; kx < 3; ++kx) {
      int ix = ox - 1 + kx;
      if (ix < 0 || ix >= OH) continue;
      acc += tp[iy*OH + ix]*wp[ky*3 + kx];
    }
  }
  yout[idx] = acc + tp[s];
}

__global__ void __launch_bounds__(256) local_kernel(
    const float* __restrict__ t1, const float* __restrict__ t2,
    const float* __restrict__ lw, const float* __restrict__ lb,
    float* __restrict__ y1, float* __restrict__ y2) {
  int blk = blockIdx.x, t = threadIdx.x;
  if (blk < 512) local_body<16>(blk*256 + t, t1, lw, lb, y1);
  else           local_body<32>((blk-512)*256 + t, t2, lw, lb, y2);
}

// ---------- stage 3: kv 1x1 conv (both branches) + q 1x1 conv ----------
__global__ void __launch_bounds__(256) kv_kernel(
    const float* __restrict__ y1, const float* __restrict__ y2,
    const float* __restrict__ wt, const float* __restrict__ kvb,
    u16* __restrict__ kt1, u16* __restrict__ vt1,
    u16* __restrict__ kt2, u16* __restrict__ vt2,
    const float* __restrict__ x, const float* __restrict__ qwt,
    const float* __restrict__ qb, u16* __restrict__ q) {
  __shared__ float sbuf[NC*16];
  int blk = blockIdx.x, t = threadIdx.x;
  if (blk < 640) {
    // ---- kv conv ----
    const float* y; u16 *kT, *vT; int hw, b, s0;
    if (blk < 128) { y = y1; kT = kt1; vT = vt1; hw = 256;  b = blk >> 6;  s0 = (blk & 63)*4; }
    else { int v = blk-128; y = y2; kT = kt2; vT = vt2; hw = 1024; b = v >> 8; s0 = (v & 255)*4; }
    #pragma unroll
    for (int j = 0; j < 4; ++j) {
      int idx = t + 256*j;
      int c = idx >> 2, i = idx & 3;
      sbuf[idx] = y[(b*NC + c)*hw + s0 + i];
    }
    __syncthreads();
    int L = 2*hw;
    for (int half = 0; half < 2; ++half) {
      int o = t + half*256;
      const float* wr = wt + o;        // column o of kvw^T, stride 512
      float bias = kvb[o];
      float acc[4];
      #pragma unroll
      for (int i = 0; i < 4; ++i) acc[i] = bias;
      #pragma unroll 4
      for (int c = 0; c < NC; ++c) {
        float w = wr[c*512];
        #pragma unroll
        for (int i = 0; i < 4; ++i) acc[i] += w*sbuf[c*4 + i];
      }
      int oc = o & 255;
      int hh2 = oc >> 6, r = oc & 63, d = r >> 1, e = r & 1;
      if (half == 0) {
        u16* kp = kT + ((size_t)((b*NHH + hh2)*L + e*hw + s0))*ND + d;
        #pragma unroll
        for (int i = 0; i < 4; ++i) kp[i*ND] = f2bf(acc[i]);
      } else {
        u16* vp = vT + ((size_t)((b*NHH + hh2)*ND + d))*L + e*hw + s0;
        #pragma unroll
        for (int i = 0; i < 4; ++i) vp[i] = f2bf(acc[i]);
      }
    }
  } else {
    // ---- q conv: 16 spatial/block, coalesced qwt weights ----
    int blk2 = blk - 640;           // 0..511
    int b = blk2 >> 8;
    int n0 = (blk2 & 255) * 16;
    #pragma unroll
    for (int j = 0; j < 16; ++j) {
      int idx = t + 256*j;
      int c = idx >> 4, i = idx & 15;
      sbuf[idx] = x[(b*NC + c)*HWIN + n0 + i];
    }
    __syncthreads();
    int half = t >> 7, oc = t & 127;
    float bias = qb[oc];
    float acc[8];
    #pragma unroll
    for (int i = 0; i < 8; ++i) acc[i] = bias;
    #pragma unroll 4
    for (int c = 0; c < NC; ++c) {
      float w = qwt[c*128 + oc];     // coalesced across lanes
      #pragma unroll
      for (int i = 0; i < 8; ++i) acc[i] += w * sbuf[c*16 + half*8 + i];
    }
    int h = oc >> 5, d = oc & 31;
    u16* qp = q + (((size_t)(b*NHH + h))*NN + n0 + half*8)*ND + d;
    #pragma unroll
    for (int i = 0; i < 8; ++i) qp[i*ND] = f2bf(acc[i]*QSCALE);
  }
}

// ---------- stage 4: MFMA flash attention, LDS-staged K/V (double-buffered) ----------
// blocks [0,512): branch1 full L=512, direct write.
// blocks [512,2560): branch2, one of 4 L-chunks; writes bf16 partial O + ssum.
__global__ void __launch_bounds__(256) attn_kernel(
    const u16* __restrict__ qbf,
    const u16* __restrict__ kt1, const u16* __restrict__ vt1, const u16* __restrict__ rct1,
    const u16* __restrict__ kt2, const u16* __restrict__ vt2, const u16* __restrict__ rct2,
    u32* __restrict__ po32, float* __restrict__ ps,
    float* __restrict__ out) {
  __shared__ u16 kbuf[2][64*72];       // K tile rows l, padded stride 72
  __shared__ u16 vbuf[2][32*72];       // V tile rows d, padded stride 72
  __shared__ u32 pbuf_all[4][16*36];   // per-wave P^T tile, u16-stride 72
  int u = blockIdx.x;
  int br, b, hh, rb, chunk;
  if (u < 512) { br = 0; b = u >> 8; hh = (u >> 6) & 3; rb = u & 63; chunk = 0; }
  else { int v = u - 512; br = 1; chunk = v & 3; rb = (v >> 2) & 63; hh = (v >> 8) & 3; b = v >> 10; }
  int L = br ? 2048 : 512;
  const u16* kT  = br ? kt2 : kt1;
  const u16* vT  = br ? vt2 : vt1;
  const u16* rcT = br ? rct2 : rct1;
  int l0base = chunk * 512;
  int tid = threadIdx.x;
  int w = tid >> 6, lane = tid & 63;
  int g = lane >> 4, lo = lane & 15;
  u32* pbuf = pbuf_all[w];
  u16* pbuf16 = (u16*)pbuf;
  int n = rb*64 + w*16 + lo;

  const u16* kbase = kT + (size_t)(b*NHH + hh)*L*ND;
  const u16* vbase = vT + (size_t)(b*NHH + hh)*ND*L;
  const u16* rcTb  = rcT + (size_t)b*L*80;

  // Q B-frag (pre-scaled by 1/sqrt(32)*log2e)
  short8 qf = *(const short8*)(qbf + (((size_t)(b*NHH + hh))*NN + n)*ND + 8*g);

  // tap-weight B-frag for RPE ext-MFMA
  float fr = ((float)n + 0.5f)*(1.f/64.f) - 0.5f;
  int ri0 = (int)floorf(fr) - 1;
  int a = (w < 2) ? rb - 2 : rb - 1;     // wave-uniform floor(fr(q0)) - 1
  int rmin = a & ~3;
  float wr4[4]; float wsum = 0.f;
  #pragma unroll
  for (int j = 0; j < 4; ++j) {
    int i = ri0 + j;
    float wv = (i >= 0 && i < 64) ? keysw(fr - (float)i) : 0.f;
    wr4[j] = wv; wsum += wv;
  }
  float invw = LOG2E / wsum;
  float wt8[8];
  #pragma unroll
  for (int s = 0; s < 8; ++s) {
    float acc = 0.f;
    #pragma unroll
    for (int j = 0; j < 4; ++j)
      acc += (ri0 + j - rmin == s) ? wr4[j]*invw : 0.f;
    wt8[s] = acc;
  }
  short8 wtf;
  {
    u32 p0 = pk_bf16(wt8[0], wt8[1]), p1 = pk_bf16(wt8[2], wt8[3]);
    u32 p2 = pk_bf16(wt8[4], wt8[5]), p3 = pk_bf16(wt8[6], wt8[7]);
    uint4 uu = make_uint4(p0, p1, p2, p3);
    wtf = __builtin_bit_cast(short8, uu);
    if (g != 0) wtf = (short8)0;
  }
  const u16* rcrow0 = rcTb + (rmin + 4);

  const f32x4 zero = {0.f, 0.f, 0.f, 0.f};
  float ssum = 0.f;
  f32x4 o0 = zero, o1 = zero;

  // staging lane roles
  int kr_row = tid >> 2, kr_col = (tid & 3)*8;   // K: 64 rows x 32
  int vr_row = tid >> 3, vr_col = (tid & 7)*8;   // V: 32 rows x 64

  auto stageLoad = [&](short8& kr, short8& vr, int l0) {
    kr = *(const short8*)(kbase + (size_t)(l0 + kr_row)*ND + kr_col);
    vr = *(const short8*)(vbase + (size_t)vr_row*L + l0 + vr_col);
  };
  auto stageStore = [&](short8 kr, short8 vr, int buf) {
    *(short8*)(kbuf[buf] + kr_row*72 + kr_col) = kr;
    *(short8*)(vbuf[buf] + vr_row*72 + vr_col) = vr;
  };
  auto loadRC = [&](uint4 (&rc)[4], int l0) {
    #pragma unroll
    for (int c = 0; c < 4; ++c) {
      const u16* arow = rcrow0 + (size_t)(l0 + 16*c + lo)*80;
      uint2 ra = *(const uint2*)arow;
      uint2 rb2 = *(const uint2*)(arow + 4);
      rc[c] = make_uint4(ra.x, ra.y, rb2.x, rb2.y);
    }
  };

  short8 kr, vr;
  uint4 rcA[4], rcB[4];
  stageLoad(kr, vr, l0base);
  loadRC(rcA, l0base);
  stageStore(kr, vr, 0);
  __syncthreads();

  for (int t = 0; t < 8; ++t) {
    int buf = t & 1;
    if (t < 7) { stageLoad(kr, vr, l0base + (t+1)*64); loadRC(rcB, l0base + (t+1)*64); }
    const u16* lk = kbuf[buf];
    const u16* lv = vbuf[buf];
    // S tiles: rc ext-MFMA chained into K.Q MFMA
    f32x4 s4[4];
    #pragma unroll
    for (int c = 0; c < 4; ++c) {
      short8 rcf = __builtin_bit_cast(short8, rcA[c]);
      f32x4 accr = __builtin_amdgcn_mfma_f32_16x16x32_bf16(rcf, wtf, zero, 0, 0, 0);
      short8 kf = *(const short8*)(lk + (16*c + lo)*72 + 8*g);
      s4[c] = __builtin_amdgcn_mfma_f32_16x16x32_bf16(kf, qf, accr, 0, 0, 0);
    }
    // max-free softmax: p = exp2(s)
    float psum = 0.f;
    u32 pk[8];
    #pragma unroll
    for (int c = 0; c < 4; ++c) {
      float p0 = exp2f(s4[c][0]), p1 = exp2f(s4[c][1]);
      float p2 = exp2f(s4[c][2]), p3 = exp2f(s4[c][3]);
      psum += (p0 + p1) + (p2 + p3);
      pk[2*c]   = pk_bf16(p0, p1);
      pk[2*c+1] = pk_bf16(p2, p3);
    }
    ssum += psum;
    #pragma unroll
    for (int c = 0; c < 4; ++c)
      *(uint2*)(pbuf + lo*36 + 8*c + 2*g) = make_uint2(pk[2*c], pk[2*c+1]);
    short8 pf0 = *(const short8*)(pbuf16 + lo*72 + 8*g);
    short8 pf1 = *(const short8*)(pbuf16 + lo*72 + 32 + 8*g);
    short8 v00 = *(const short8*)(lv + lo*72 + 8*g);
    short8 v01 = *(const short8*)(lv + lo*72 + 32 + 8*g);
    short8 v10 = *(const short8*)(lv + (16+lo)*72 + 8*g);
    short8 v11 = *(const short8*)(lv + (16+lo)*72 + 32 + 8*g);
    o0 = __builtin_amdgcn_mfma_f32_16x16x32_bf16(v00, pf0, o0, 0, 0, 0);
    o1 = __builtin_amdgcn_mfma_f32_16x16x32_bf16(v10, pf0, o1, 0, 0, 0);
    o0 = __builtin_amdgcn_mfma_f32_16x16x32_bf16(v01, pf1, o0, 0, 0, 0);
    o1 = __builtin_amdgcn_mfma_f32_16x16x32_bf16(v11, pf1, o1, 0, 0, 0);
    if (t < 7) {
      stageStore(kr, vr, buf ^ 1);
      #pragma unroll
      for (int j = 0; j < 4; ++j) rcA[j] = rcB[j];
    }
    __syncthreads();
  }

  ssum += __shfl_xor(ssum, 16, 64);
  ssum += __shfl_xor(ssum, 32, 64);
  if (br == 0) {
    float inv = 1.f/ssum;
    f32x4 w0 = o0*inv, w1 = o1*inv;
    float* op = out + ((size_t)((b*NC + hh*64 + rb)*64 + (w*16 + lo)))*64;
    *(f32x4*)(op + 4*g)      = w0;
    *(f32x4*)(op + 16 + 4*g) = w1;
  } else {
    int bh = b*NHH + hh;
    int row = bh*NN + n;
    u32* pop = po32 + ((size_t)chunk*32768 + row)*16;    // chunk-major
    pop[2*g]     = pk_bf16(o0[0], o0[1]);
    pop[2*g + 1] = pk_bf16(o0[2], o0[3]);
    pop[8 + 2*g]     = pk_bf16(o1[0], o1[1]);
    pop[8 + 2*g + 1] = pk_bf16(o1[2], o1[3]);
    if (g == 0) ps[(size_t)chunk*32768 + row] = ssum;
  }
}

// ---------- stage 5: combine branch-2 chunk partials (coalesced, 4 thr/row) ----------
__global__ void __launch_bounds__(256) combine_kernel(
    const u32* __restrict__ po32, const float* __restrict__ ps,
    float* __restrict__ out) {
  int gid = blockIdx.x*256 + threadIdx.x;   // 0..131071
  int row = gid >> 2, part = gid & 3;       // row 0..32767; part = 8-float group
  float sden = ps[row] + ps[32768 + row] + ps[65536 + row] + ps[98304 + row];
  float inv = 1.f/sden;
  float o[8];
  #pragma unroll
  for (int i = 0; i < 8; ++i) o[i] = 0.f;
  #pragma unroll
  for (int chunk = 0; chunk < 4; ++chunk) {
    const u32* pp = po32 + ((size_t)chunk*32768 + row)*16 + part*4;
    uint4 a = *(const uint4*)pp;            // coalesced 16B
    u32 av[4] = {a.x, a.y, a.z, a.w};
    #pragma unroll
    for (int j = 0; j < 4; ++j) {
      o[2*j]   += __uint_as_float(av[j] << 16);
      o[2*j+1] += __uint_as_float(av[j] & 0xffff0000u);
    }
  }
  int bh = row >> 12, n = row & 4095;
  float* op = out + ((size_t)(((bh>>2)*NC + (bh&3)*64 + (n>>6))*64 + (n&63)))*64 + 32 + part*8;
  #pragma unroll
  for (int j = 0; j < 2; ++j) {
    f32x4 v = {o[4*j]*inv, o[4*j+1]*inv, o[4*j+2]*inv, o[4*j+3]*inv};
    *(f32x4*)(op + 4*j) = v;
  }
}

extern "C" void kernel_launch(void* const* d_in, const int* in_sizes, int n_in,
                              void* d_out, int out_size, void* d_ws, size_t ws_size,
                              hipStream_t stream) {
  const float* x    = (const float*)d_in[0];
  const float* rpe  = (const float*)d_in[1];
  const float* qw   = (const float*)d_in[2];
  const float* qb   = (const float*)d_in[3];
  const float* kvw  = (const float*)d_in[4];
  const float* kvb  = (const float*)d_in[5];
  const float* dw1  = (const float*)d_in[6];
  const float* bn11 = (const float*)d_in[7];
  const float* pw1  = (const float*)d_in[8];
  const float* bn12 = (const float*)d_in[9];
  const float* dw2  = (const float*)d_in[10];
  const float* bn21 = (const float*)d_in[11];
  const float* pw2  = (const float*)d_in[12];
  const float* bn22 = (const float*)d_in[13];
  const float* lw   = (const float*)d_in[14];
  const float* lb   = (const float*)d_in[15];
  float* out = (float*)d_out;
  float* ws  = (float*)d_ws;

  float* t1   = ws + OFF_T1;
  float* y1   = ws + OFF_Y1;
  float* t2   = ws + OFF_T2;
  float* y2   = ws + OFF_Y2;
  u16*   q    = (u16*)(ws + OFF_Q);
  u16*   kt1  = (u16*)(ws + OFF_KT1);
  u16*   vt1  = (u16*)(ws + OFF_VT1);
  u16*   kt2  = (u16*)(ws + OFF_KT2);
  u16*   vt2  = (u16*)(ws + OFF_VT2);
  u16*   rct1 = (u16*)(ws + OFF_RCT1);
  u16*   rct2 = (u16*)(ws + OFF_RCT2);
  float* wt   = ws + OFF_WT;
  u32*   po32 = (u32*)(ws + OFF_PO);
  float* ps   = ws + OFF_PS;
  float* qwt  = ws + OFF_QWT;

  hipLaunchKernelGGL(prep_kernel, dim3(4000), dim3(256), 0, stream,
                     x, dw1, bn11, pw1, bn12, t1, dw2, bn21, pw2, bn22, t2,
                     rpe, rct1, rct2, kvw, wt, qw, qwt);
  hipLaunchKernelGGL(local_kernel, dim3(2560), dim3(256), 0, stream,
                     t1, t2, lw, lb, y1, y2);
  hipLaunchKernelGGL(kv_kernel, dim3(1152), dim3(256), 0, stream,
                     y1, y2, wt, kvb, kt1, vt1, kt2, vt2, x, qwt, qb, q);
  hipLaunchKernelGGL(attn_kernel, dim3(2560), dim3(256), 0, stream,
                     q, kt1, vt1, rct1, kt2, vt2, rct2, po32, ps, out);
  hipLaunchKernelGGL(combine_kernel, dim3(512), dim3(256), 0, stream,
                     po32, ps, out);
}

// Round 10
// 190.529 us; speedup vs baseline: 2.1013x; 1.0264x over previous
//
#include <hip/hip_runtime.h>
#include <hip/hip_bf16.h>
#include <math.h>

#define NB 2
#define NC 256
#define HWIN 4096
#define NN 4096
#define ND 32
#define NHH 4
#define EPSV 1e-5f

typedef short short8 __attribute__((ext_vector_type(8)));
typedef float f32x4 __attribute__((ext_vector_type(4)));
typedef unsigned short u16;
typedef unsigned int u32;

// workspace offsets (float32 units)
#define OFF_T1   0          // 131072
#define OFF_T2   262144     // 524288
#define OFF_Q    1310720    // 524288 (bf16 x 1048576)
#define OFF_KT1  1835008    // 65536
#define OFF_VT1  1900544    // 65536
#define OFF_KT2  1966080    // 262144
#define OFF_VT2  2228224    // 262144
#define OFF_RCT1 2490368    // 40960
#define OFF_RCT2 2531328    // 163840
#define OFF_WT   2695168    // 131072  (kvw^T, f32 [c][o] 256x512)
#define OFF_PO   2826240    // 2097152 u32: po[chunk][32768 rows][16]
#define OFF_PS   4923392    // 131072: ps[chunk][32768 rows]
#define OFF_QWT  5054464    // 32768   (qw^T, f32 [c][oc] 256x128)
// end 5087232 floats = 20.3 MB

#define QSCALE 0.2550437314857726f   // 1/sqrt(32) * log2(e)
#define LOG2E  1.4426950408889634f

__device__ __forceinline__ u16 f2bf(float x) {   // f32 -> bf16 RNE
  unsigned u = __float_as_uint(x);
  u += 0x7fffu + ((u >> 16) & 1u);
  return (u16)(u >> 16);
}

__device__ __forceinline__ u32 pk_bf16(float a, float b) {  // packed RNE cvt
  __hip_bfloat162 h = __float22bfloat162_rn(make_float2(a, b));
  u32 r; __builtin_memcpy(&r, &h, 4);
  return r;
}

__device__ __forceinline__ float keysw(float t) {  // Keys cubic, a=-0.5
  t = fabsf(t);
  float w;
  if (t < 1.f)       w = ((1.5f*t - 2.5f)*t)*t + 1.f;
  else if (t < 2.f)  w = ((-0.5f*t + 2.5f)*t - 4.f)*t + 2.f;
  else               w = 0.f;
  return w;
}

// ---------- device bodies ----------
template<int KS, int STR, int PAD, int OH>
__device__ __forceinline__ void dwconv_body(int idx, const float* __restrict__ x,
    const float* __restrict__ dww, const float* __restrict__ bn1,
    const float* __restrict__ pww, const float* __restrict__ bn2,
    float* __restrict__ tout) {
  const int hw = OH*OH;
  int s = idx % hw; int c = (idx/hw) % NC; int b = idx/(hw*NC);
  int oy = s / OH, ox = s % OH;
  const float* xp = x + (b*NC + c)*HWIN;
  const float* wp = dww + c*KS*KS;
  float acc = 0.f;
  #pragma unroll
  for (int ky = 0; ky < KS; ++ky) {
    int iy = oy*STR - PAD + ky;
    if (iy < 0 || iy >= 64) continue;
    #pragma unroll
    for (int kx = 0; kx < KS; ++kx) {
      int ix = ox*STR - PAD + kx;
      if (ix < 0 || ix >= 64) continue;
      acc += xp[iy*64 + ix] * wp[ky*KS + kx];
    }
  }
  float s1 = bn1[c] * rsqrtf(bn1[3*NC + c] + EPSV);
  float z = (acc - bn1[2*NC + c])*s1 + bn1[NC + c];
  z = fmaxf(z, 0.f);
  float s2 = bn2[c] * rsqrtf(bn2[3*NC + c] + EPSV);
  z = z * (pww[c]*s2) + (bn2[NC + c] - bn2[2*NC + c]*s2);
  tout[idx] = z;
}

__device__ __forceinline__ void rpe_body(int idx, const float* __restrict__ rpe,
                                         u16* __restrict__ rcT, int L, int ch) {
  int r = idx & 63; int l = (idx >> 6) % L; int b = idx / (64*L);
  float f = ((float)l + 0.5f)*(64.f/(float)L) - 0.5f;
  int i0 = (int)floorf(f) - 1;
  const float* rp = rpe + ((b*2 + ch)*64 + r)*64;
  float v = 0.f, wsum = 0.f;
  #pragma unroll
  for (int j = 0; j < 4; ++j) {
    int i = i0 + j;
    if (i >= 0 && i < 64) {
      float w = keysw(f - (float)i);
      v += w * rp[i]; wsum += w;
    }
  }
  rcT[((size_t)(b*L + l))*80 + 4 + r] = f2bf(v / wsum);
}

// ---------- stage 1: dwconv1 + dwconv2 + rpe1 + rpe2 + kvw^T + qw^T ----------
__global__ void __launch_bounds__(256) prep_kernel(
    const float* __restrict__ x,
    const float* __restrict__ dw1, const float* __restrict__ bn11,
    const float* __restrict__ pw1, const float* __restrict__ bn12, float* __restrict__ t1,
    const float* __restrict__ dw2, const float* __restrict__ bn21,
    const float* __restrict__ pw2, const float* __restrict__ bn22, float* __restrict__ t2,
    const float* __restrict__ rpe, u16* __restrict__ rct1, u16* __restrict__ rct2,
    const float* __restrict__ kvw, float* __restrict__ wt,
    const float* __restrict__ qw, float* __restrict__ qwt) {
  int blk = blockIdx.x;
  int t = threadIdx.x;
  if (blk < 512) {
    dwconv_body<7,4,3,16>(blk*256 + t, x, dw1, bn11, pw1, bn12, t1);
  } else if (blk < 2560) {
    dwconv_body<5,2,2,32>((blk-512)*256 + t, x, dw2, bn21, pw2, bn22, t2);
  } else if (blk < 2816) {
    rpe_body((blk-2560)*256 + t, rpe, rct1, 512, 0);
  } else if (blk < 3840) {
    rpe_body((blk-2816)*256 + t, rpe, rct2, 2048, 1);
  } else if (blk < 3968) {
    // kvw transpose: wt[c][o] = kvw[o][c]   (512x256 -> 256x512)
    int base = ((blk-3840)*256 + t)*4;
    float4 vv = *(const float4*)(kvw + base);
    int o = base >> 8, c = base & 255;
    wt[(c+0)*512 + o] = vv.x;
    wt[(c+1)*512 + o] = vv.y;
    wt[(c+2)*512 + o] = vv.z;
    wt[(c+3)*512 + o] = vv.w;
  } else {
    // qw transpose: qwt[c][oc] = qw[oc][c]  (128x256 -> 256x128)
    int base = ((blk-3968)*256 + t)*4;
    float4 vv = *(const float4*)(qw + base);
    int oc = base >> 8, c = base & 255;
    qwt[(c+0)*128 + oc] = vv.x;
    qwt[(c+1)*128 + oc] = vv.y;
    qwt[(c+2)*128 + oc] = vv.z;
    qwt[(c+3)*128 + oc] = vv.w;
  }
}

// ---------- stage 2: fused local 3x3 + kv 1x1 (both branches) + q 1x1 ----------
// blocks [0,64): br1 strips, [64,320): br2 strips, [320,832): q conv.
__global__ void __launch_bounds__(256) localkv_kernel(
    const float* __restrict__ t1in, const float* __restrict__ t2in,
    const float* __restrict__ lw, const float* __restrict__ lb,
    const float* __restrict__ wt, const float* __restrict__ kvb,
    u16* __restrict__ kt1, u16* __restrict__ vt1,
    u16* __restrict__ kt2, u16* __restrict__ vt2,
    const float* __restrict__ x, const float* __restrict__ qwt,
    const float* __restrict__ qb, u16* __restrict__ q) {
  __shared__ float sbuf[NC*16];
  int blk = blockIdx.x, tid = threadIdx.x;
  if (blk < 320) {
    // ---- fused local+kv over an 8-spatial strip ----
    const float* tin; u16 *kT, *vT; int OH, hw, b, s0;
    if (blk < 64) { tin = t1in; kT = kt1; vT = vt1; OH = 16; hw = 256;  b = blk >> 5;  s0 = (blk & 31)*8; }
    else { int v = blk-64; tin = t2in; kT = kt2; vT = vt2; OH = 32; hw = 1024; b = v >> 7; s0 = (v & 127)*8; }
    int oy = s0 / OH, ox0 = s0 % OH;
    // stage A: y(strip) -> LDS, stride 12 (broadcast-friendly, 16B aligned)
    int ci = tid >> 3, i = tid & 7;
    int ox = ox0 + i;
    #pragma unroll
    for (int p = 0; p < 8; ++p) {
      int c = p*32 + ci;
      const float* tp = tin + (b*NC + c)*hw;
      const float* wp = lw + c*9;
      float acc = lb[c];
      #pragma unroll
      for (int dy = 0; dy < 3; ++dy) {
        int iy = oy + dy - 1;
        if (iy < 0 || iy >= OH) continue;
        #pragma unroll
        for (int dx = 0; dx < 3; ++dx) {
          int ix = ox + dx - 1;
          if (ix < 0 || ix >= OH) continue;
          acc += tp[iy*OH + ix]*wp[dy*3 + dx];
        }
      }
      acc += tp[oy*OH + ox];
      sbuf[c*12 + i] = acc;
    }
    __syncthreads();
    // stage B: kv conv; this thread computes K row (o=tid) and V row (o=tid+256)
    float acc0[8], acc1[8];
    float b0 = kvb[tid], b1 = kvb[tid + 256];
    #pragma unroll
    for (int j = 0; j < 8; ++j) { acc0[j] = b0; acc1[j] = b1; }
    #pragma unroll 4
    for (int c = 0; c < NC; ++c) {
      f32x4 ya = *(const f32x4*)(sbuf + c*12);
      f32x4 yb = *(const f32x4*)(sbuf + c*12 + 4);
      float w0 = wt[c*512 + tid];
      float w1 = wt[c*512 + tid + 256];
      #pragma unroll
      for (int j = 0; j < 4; ++j) {
        acc0[j]   += w0*ya[j];  acc0[4+j] += w0*yb[j];
        acc1[j]   += w1*ya[j];  acc1[4+j] += w1*yb[j];
      }
    }
    int hh2 = tid >> 6, r = tid & 63, d = r >> 1, e = r & 1;
    int L = 2*hw;
    u16* kp = kT + ((size_t)((b*NHH + hh2)*L + e*hw + s0))*ND + d;
    #pragma unroll
    for (int j = 0; j < 8; ++j) kp[j*ND] = f2bf(acc0[j]);
    u16* vp = vT + ((size_t)((b*NHH + hh2)*ND + d))*L + e*hw + s0;
    #pragma unroll
    for (int j = 0; j < 8; ++j) vp[j] = f2bf(acc1[j]);
  } else {
    // ---- q conv: 16 spatial/block, coalesced qwt weights ----
    int blk2 = blk - 320;           // 0..511
    int b = blk2 >> 8;
    int n0 = (blk2 & 255) * 16;
    #pragma unroll
    for (int j = 0; j < 16; ++j) {
      int idx = tid + 256*j;
      int c = idx >> 4, i = idx & 15;
      sbuf[idx] = x[(b*NC + c)*HWIN + n0 + i];
    }
    __syncthreads();
    int half = tid >> 7, oc = tid & 127;
    float bias = qb[oc];
    float acc[8];
    #pragma unroll
    for (int i = 0; i < 8; ++i) acc[i] = bias;
    #pragma unroll 4
    for (int c = 0; c < NC; ++c) {
      float w = qwt[c*128 + oc];     // coalesced across lanes
      #pragma unroll
      for (int i = 0; i < 8; ++i) acc[i] += w * sbuf[c*16 + half*8 + i];
    }
    int h = oc >> 5, d = oc & 31;
    u16* qp = q + (((size_t)(b*NHH + h))*NN + n0 + half*8)*ND + d;
    #pragma unroll
    for (int i = 0; i < 8; ++i) qp[i*ND] = f2bf(acc[i]*QSCALE);
  }
}

// ---------- stage 3: MFMA flash attention, LDS-staged K/V (double-buffered) ----------
// blocks [0,512): branch1 full L=512, direct write.
// blocks [512,2560): branch2, one of 4 L-chunks; writes bf16 partial O + ssum.
__global__ void __launch_bounds__(256) attn_kernel(
    const u16* __restrict__ qbf,
    const u16* __restrict__ kt1, const u16* __restrict__ vt1, const u16* __restrict__ rct1,
    const u16* __restrict__ kt2, const u16* __restrict__ vt2, const u16* __restrict__ rct2,
    u32* __restrict__ po32, float* __restrict__ ps,
    float* __restrict__ out) {
  __shared__ u16 kbuf[2][64*72];       // K tile rows l, padded stride 72
  __shared__ u16 vbuf[2][32*72];       // V tile rows d, padded stride 72
  __shared__ u32 pbuf_all[4][16*36];   // per-wave P^T tile, u16-stride 72
  int u = blockIdx.x;
  int br, b, hh, rb, chunk;
  if (u < 512) { br = 0; b = u >> 8; hh = (u >> 6) & 3; rb = u & 63; chunk = 0; }
  else { int v = u - 512; br = 1; chunk = v & 3; rb = (v >> 2) & 63; hh = (v >> 8) & 3; b = v >> 10; }
  int L = br ? 2048 : 512;
  const u16* kT  = br ? kt2 : kt1;
  const u16* vT  = br ? vt2 : vt1;
  const u16* rcT = br ? rct2 : rct1;
  int l0base = chunk * 512;
  int tid = threadIdx.x;
  int w = tid >> 6, lane = tid & 63;
  int g = lane >> 4, lo = lane & 15;
  u32* pbuf = pbuf_all[w];
  u16* pbuf16 = (u16*)pbuf;
  int n = rb*64 + w*16 + lo;

  const u16* kbase = kT + (size_t)(b*NHH + hh)*L*ND;
  const u16* vbase = vT + (size_t)(b*NHH + hh)*ND*L;
  const u16* rcTb  = rcT + (size_t)b*L*80;

  // Q B-frag (pre-scaled by 1/sqrt(32)*log2e)
  short8 qf = *(const short8*)(qbf + (((size_t)(b*NHH + hh))*NN + n)*ND + 8*g);

  // tap-weight B-frag for RPE ext-MFMA
  float fr = ((float)n + 0.5f)*(1.f/64.f) - 0.5f;
  int ri0 = (int)floorf(fr) - 1;
  int a = (w < 2) ? rb - 2 : rb - 1;     // wave-uniform floor(fr(q0)) - 1
  int rmin = a & ~3;
  float wr4[4]; float wsum = 0.f;
  #pragma unroll
  for (int j = 0; j < 4; ++j) {
    int i = ri0 + j;
    float wv = (i >= 0 && i < 64) ? keysw(fr - (float)i) : 0.f;
    wr4[j] = wv; wsum += wv;
  }
  float invw = LOG2E / wsum;
  float wt8[8];
  #pragma unroll
  for (int s = 0; s < 8; ++s) {
    float acc = 0.f;
    #pragma unroll
    for (int j = 0; j < 4; ++j)
      acc += (ri0 + j - rmin == s) ? wr4[j]*invw : 0.f;
    wt8[s] = acc;
  }
  short8 wtf;
  {
    u32 p0 = pk_bf16(wt8[0], wt8[1]), p1 = pk_bf16(wt8[2], wt8[3]);
    u32 p2 = pk_bf16(wt8[4], wt8[5]), p3 = pk_bf16(wt8[6], wt8[7]);
    uint4 uu = make_uint4(p0, p1, p2, p3);
    wtf = __builtin_bit_cast(short8, uu);
    if (g != 0) wtf = (short8)0;
  }
  const u16* rcrow0 = rcTb + (rmin + 4);

  const f32x4 zero = {0.f, 0.f, 0.f, 0.f};
  float ssum = 0.f;
  f32x4 o0 = zero, o1 = zero;

  // staging lane roles
  int kr_row = tid >> 2, kr_col = (tid & 3)*8;   // K: 64 rows x 32
  int vr_row = tid >> 3, vr_col = (tid & 7)*8;   // V: 32 rows x 64

  auto stageLoad = [&](short8& kr, short8& vr, int l0) {
    kr = *(const short8*)(kbase + (size_t)(l0 + kr_row)*ND + kr_col);
    vr = *(const short8*)(vbase + (size_t)vr_row*L + l0 + vr_col);
  };
  auto stageStore = [&](short8 kr, short8 vr, int buf) {
    *(short8*)(kbuf[buf] + kr_row*72 + kr_col) = kr;
    *(short8*)(vbuf[buf] + vr_row*72 + vr_col) = vr;
  };
  auto loadRC = [&](uint4 (&rc)[4], int l0) {
    #pragma unroll
    for (int c = 0; c < 4; ++c) {
      const u16* arow = rcrow0 + (size_t)(l0 + 16*c + lo)*80;
      uint2 ra = *(const uint2*)arow;
      uint2 rb2 = *(const uint2*)(arow + 4);
      rc[c] = make_uint4(ra.x, ra.y, rb2.x, rb2.y);
    }
  };

  short8 kr, vr;
  uint4 rcA[4], rcB[4];
  stageLoad(kr, vr, l0base);
  loadRC(rcA, l0base);
  stageStore(kr, vr, 0);
  __syncthreads();

  for (int t = 0; t < 8; ++t) {
    int buf = t & 1;
    if (t < 7) { stageLoad(kr, vr, l0base + (t+1)*64); loadRC(rcB, l0base + (t+1)*64); }
    const u16* lk = kbuf[buf];
    const u16* lv = vbuf[buf];
    // S tiles: rc ext-MFMA chained into K.Q MFMA
    f32x4 s4[4];
    #pragma unroll
    for (int c = 0; c < 4; ++c) {
      short8 rcf = __builtin_bit_cast(short8, rcA[c]);
      f32x4 accr = __builtin_amdgcn_mfma_f32_16x16x32_bf16(rcf, wtf, zero, 0, 0, 0);
      short8 kf = *(const short8*)(lk + (16*c + lo)*72 + 8*g);
      s4[c] = __builtin_amdgcn_mfma_f32_16x16x32_bf16(kf, qf, accr, 0, 0, 0);
    }
    // max-free softmax: p = exp2(s)
    float psum = 0.f;
    u32 pk[8];
    #pragma unroll
    for (int c = 0; c < 4; ++c) {
      float p0 = exp2f(s4[c][0]), p1 = exp2f(s4[c][1]);
      float p2 = exp2f(s4[c][2]), p3 = exp2f(s4[c][3]);
      psum += (p0 + p1) + (p2 + p3);
      pk[2*c]   = pk_bf16(p0, p1);
      pk[2*c+1] = pk_bf16(p2, p3);
    }
    ssum += psum;
    #pragma unroll
    for (int c = 0; c < 4; ++c)
      *(uint2*)(pbuf + lo*36 + 8*c + 2*g) = make_uint2(pk[2*c], pk[2*c+1]);
    short8 pf0 = *(const short8*)(pbuf16 + lo*72 + 8*g);
    short8 pf1 = *(const short8*)(pbuf16 + lo*72 + 32 + 8*g);
    short8 v00 = *(const short8*)(lv + lo*72 + 8*g);
    short8 v01 = *(const short8*)(lv + lo*72 + 32 + 8*g);
    short8 v10 = *(const short8*)(lv + (16+lo)*72 + 8*g);
    short8 v11 = *(const short8*)(lv + (16+lo)*72 + 32 + 8*g);
    o0 = __builtin_amdgcn_mfma_f32_16x16x32_bf16(v00, pf0, o0, 0, 0, 0);
    o1 = __builtin_amdgcn_mfma_f32_16x16x32_bf16(v10, pf0, o1, 0, 0, 0);
    o0 = __builtin_amdgcn_mfma_f32_16x16x32_bf16(v01, pf1, o0, 0, 0, 0);
    o1 = __builtin_amdgcn_mfma_f32_16x16x32_bf16(v11, pf1, o1, 0, 0, 0);
    if (t < 7) {
      stageStore(kr, vr, buf ^ 1);
      #pragma unroll
      for (int j = 0; j < 4; ++j) rcA[j] = rcB[j];
    }
    __syncthreads();
  }

  ssum += __shfl_xor(ssum, 16, 64);
  ssum += __shfl_xor(ssum, 32, 64);
  if (br == 0) {
    float inv = 1.f/ssum;
    f32x4 w0 = o0*inv, w1 = o1*inv;
    float* op = out + ((size_t)((b*NC + hh*64 + rb)*64 + (w*16 + lo)))*64;
    *(f32x4*)(op + 4*g)      = w0;
    *(f32x4*)(op + 16 + 4*g) = w1;
  } else {
    int bh = b*NHH + hh;
    int row = bh*NN + n;
    u32* pop = po32 + ((size_t)chunk*32768 + row)*16;    // chunk-major
    pop[2*g]     = pk_bf16(o0[0], o0[1]);
    pop[2*g + 1] = pk_bf16(o0[2], o0[3]);
    pop[8 + 2*g]     = pk_bf16(o1[0], o1[1]);
    pop[8 + 2*g + 1] = pk_bf16(o1[2], o1[3]);
    if (g == 0) ps[(size_t)chunk*32768 + row] = ssum;
  }
}

// ---------- stage 4: combine branch-2 chunk partials (coalesced, 4 thr/row) ----------
__global__ void __launch_bounds__(256) combine_kernel(
    const u32* __restrict__ po32, const float* __restrict__ ps,
    float* __restrict__ out) {
  int gid = blockIdx.x*256 + threadIdx.x;   // 0..131071
  int row = gid >> 2, part = gid & 3;       // row 0..32767; part = 8-float group
  float sden = ps[row] + ps[32768 + row] + ps[65536 + row] + ps[98304 + row];
  float inv = 1.f/sden;
  float o[8];
  #pragma unroll
  for (int i = 0; i < 8; ++i) o[i] = 0.f;
  #pragma unroll
  for (int chunk = 0; chunk < 4; ++chunk) {
    const u32* pp = po32 + ((size_t)chunk*32768 + row)*16 + part*4;
    uint4 a = *(const uint4*)pp;            // coalesced 16B
    u32 av[4] = {a.x, a.y, a.z, a.w};
    #pragma unroll
    for (int j = 0; j < 4; ++j) {
      o[2*j]   += __uint_as_float(av[j] << 16);
      o[2*j+1] += __uint_as_float(av[j] & 0xffff0000u);
    }
  }
  int bh = row >> 12, n = row & 4095;
  float* op = out + ((size_t)(((bh>>2)*NC + (bh&3)*64 + (n>>6))*64 + (n&63)))*64 + 32 + part*8;
  #pragma unroll
  for (int j = 0; j < 2; ++j) {
    f32x4 v = {o[4*j]*inv, o[4*j+1]*inv, o[4*j+2]*inv, o[4*j+3]*inv};
    *(f32x4*)(op + 4*j) = v;
  }
}

extern "C" void kernel_launch(void* const* d_in, const int* in_sizes, int n_in,
                              void* d_out, int out_size, void* d_ws, size_t ws_size,
                              hipStream_t stream) {
  const float* x    = (const float*)d_in[0];
  const float* rpe  = (const float*)d_in[1];
  const float* qw   = (const float*)d_in[2];
  const float* qb   = (const float*)d_in[3];
  const float* kvw  = (const float*)d_in[4];
  const float* kvb  = (const float*)d_in[5];
  const float* dw1  = (const float*)d_in[6];
  const float* bn11 = (const float*)d_in[7];
  const float* pw1  = (const float*)d_in[8];
  const float* bn12 = (const float*)d_in[9];
  const float* dw2  = (const float*)d_in[10];
  const float* bn21 = (const float*)d_in[11];
  const float* pw2  = (const float*)d_in[12];
  const float* bn22 = (const float*)d_in[13];
  const float* lw   = (const float*)d_in[14];
  const float* lb   = (const float*)d_in[15];
  float* out = (float*)d_out;
  float* ws  = (float*)d_ws;

  float* t1   = ws + OFF_T1;
  float* t2   = ws + OFF_T2;
  u16*   q    = (u16*)(ws + OFF_Q);
  u16*   kt1  = (u16*)(ws + OFF_KT1);
  u16*   vt1  = (u16*)(ws + OFF_VT1);
  u16*   kt2  = (u16*)(ws + OFF_KT2);
  u16*   vt2  = (u16*)(ws + OFF_VT2);
  u16*   rct1 = (u16*)(ws + OFF_RCT1);
  u16*   rct2 = (u16*)(ws + OFF_RCT2);
  float* wt   = ws + OFF_WT;
  u32*   po32 = (u32*)(ws + OFF_PO);
  float* ps   = ws + OFF_PS;
  float* qwt  = ws + OFF_QWT;

  hipLaunchKernelGGL(prep_kernel, dim3(4000), dim3(256), 0, stream,
                     x, dw1, bn11, pw1, bn12, t1, dw2, bn21, pw2, bn22, t2,
                     rpe, rct1, rct2, kvw, wt, qw, qwt);
  hipLaunchKernelGGL(localkv_kernel, dim3(832), dim3(256), 0, stream,
                     t1, t2, lw, lb, wt, kvb, kt1, vt1, kt2, vt2, x, qwt, qb, q);
  hipLaunchKernelGGL(attn_kernel, dim3(2560), dim3(256), 0, stream,
                     q, kt1, vt1, rct1, kt2, vt2, rct2, po32, ps, out);
  hipLaunchKernelGGL(combine_kernel, dim3(512), dim3(256), 0, stream,
                     po32, ps, out);
}

// Round 11
// 189.850 us; speedup vs baseline: 2.1088x; 1.0036x over previous
//
#include <hip/hip_runtime.h>
#include <hip/hip_bf16.h>
#include <math.h>

#define NB 2
#define NC 256
#define HWIN 4096
#define NN 4096
#define ND 32
#define NHH 4
#define EPSV 1e-5f

typedef short short8 __attribute__((ext_vector_type(8)));
typedef float f32x4 __attribute__((ext_vector_type(4)));
typedef unsigned short u16;
typedef unsigned int u32;

// workspace offsets (float32 units)
#define OFF_T1   0          // 131072
#define OFF_T2   262144     // 524288
#define OFF_Q    1310720    // 524288 (bf16 x 1048576)
#define OFF_KT1  1835008    // 65536
#define OFF_VT1  1900544    // 65536
#define OFF_KT2  1966080    // 262144
#define OFF_VT2  2228224    // 262144
#define OFF_RCT1 2490368    // 40960
#define OFF_RCT2 2531328    // 163840
#define OFF_WT   2695168    // 131072  (kvw^T, f32 [c][o] 256x512)
#define OFF_PO   2826240    // 2097152 u32: po[chunk][32768 rows][16]
#define OFF_PS   4923392    // 131072: ps[chunk][32768 rows]
#define OFF_QWT  5054464    // 32768   (qw^T, f32 [c][oc] 256x128)
// end 5087232 floats = 20.3 MB

#define QSCALE 0.2550437314857726f   // 1/sqrt(32) * log2(e)
#define LOG2E  1.4426950408889634f

__device__ __forceinline__ u16 f2bf(float x) {   // f32 -> bf16 RNE
  unsigned u = __float_as_uint(x);
  u += 0x7fffu + ((u >> 16) & 1u);
  return (u16)(u >> 16);
}

__device__ __forceinline__ u32 pk_bf16(float a, float b) {  // packed RNE cvt
  __hip_bfloat162 h = __float22bfloat162_rn(make_float2(a, b));
  u32 r; __builtin_memcpy(&r, &h, 4);
  return r;
}

__device__ __forceinline__ float keysw(float t) {  // Keys cubic, a=-0.5
  t = fabsf(t);
  float w;
  if (t < 1.f)       w = ((1.5f*t - 2.5f)*t)*t + 1.f;
  else if (t < 2.f)  w = ((-0.5f*t + 2.5f)*t - 4.f)*t + 2.f;
  else               w = 0.f;
  return w;
}

// ---------- device bodies ----------
template<int KS, int STR, int PAD, int OH>
__device__ __forceinline__ void dwconv_body(int idx, const float* __restrict__ x,
    const float* __restrict__ dww, const float* __restrict__ bn1,
    const float* __restrict__ pww, const float* __restrict__ bn2,
    float* __restrict__ tout) {
  const int hw = OH*OH;
  int s = idx % hw; int c = (idx/hw) % NC; int b = idx/(hw*NC);
  int oy = s / OH, ox = s % OH;
  const float* xp = x + (b*NC + c)*HWIN;
  const float* wp = dww + c*KS*KS;
  float acc = 0.f;
  #pragma unroll
  for (int ky = 0; ky < KS; ++ky) {
    int iy = oy*STR - PAD + ky;
    if (iy < 0 || iy >= 64) continue;
    #pragma unroll
    for (int kx = 0; kx < KS; ++kx) {
      int ix = ox*STR - PAD + kx;
      if (ix < 0 || ix >= 64) continue;
      acc += xp[iy*64 + ix] * wp[ky*KS + kx];
    }
  }
  float s1 = bn1[c] * rsqrtf(bn1[3*NC + c] + EPSV);
  float z = (acc - bn1[2*NC + c])*s1 + bn1[NC + c];
  z = fmaxf(z, 0.f);
  float s2 = bn2[c] * rsqrtf(bn2[3*NC + c] + EPSV);
  z = z * (pww[c]*s2) + (bn2[NC + c] - bn2[2*NC + c]*s2);
  tout[idx] = z;
}

__device__ __forceinline__ void rpe_body(int idx, const float* __restrict__ rpe,
                                         u16* __restrict__ rcT, int L, int ch) {
  int r = idx & 63; int l = (idx >> 6) % L; int b = idx / (64*L);
  float f = ((float)l + 0.5f)*(64.f/(float)L) - 0.5f;
  int i0 = (int)floorf(f) - 1;
  const float* rp = rpe + ((b*2 + ch)*64 + r)*64;
  float v = 0.f, wsum = 0.f;
  #pragma unroll
  for (int j = 0; j < 4; ++j) {
    int i = i0 + j;
    if (i >= 0 && i < 64) {
      float w = keysw(f - (float)i);
      v += w * rp[i]; wsum += w;
    }
  }
  rcT[((size_t)(b*L + l))*80 + 4 + r] = f2bf(v / wsum);
}

// ---------- stage 1: dwconv1 + dwconv2 + rpe1 + rpe2 + kvw^T + qw^T ----------
__global__ void __launch_bounds__(256) prep_kernel(
    const float* __restrict__ x,
    const float* __restrict__ dw1, const float* __restrict__ bn11,
    const float* __restrict__ pw1, const float* __restrict__ bn12, float* __restrict__ t1,
    const float* __restrict__ dw2, const float* __restrict__ bn21,
    const float* __restrict__ pw2, const float* __restrict__ bn22, float* __restrict__ t2,
    const float* __restrict__ rpe, u16* __restrict__ rct1, u16* __restrict__ rct2,
    const float* __restrict__ kvw, float* __restrict__ wt,
    const float* __restrict__ qw, float* __restrict__ qwt) {
  int blk = blockIdx.x;
  int t = threadIdx.x;
  if (blk < 512) {
    dwconv_body<7,4,3,16>(blk*256 + t, x, dw1, bn11, pw1, bn12, t1);
  } else if (blk < 2560) {
    dwconv_body<5,2,2,32>((blk-512)*256 + t, x, dw2, bn21, pw2, bn22, t2);
  } else if (blk < 2816) {
    rpe_body((blk-2560)*256 + t, rpe, rct1, 512, 0);
  } else if (blk < 3840) {
    rpe_body((blk-2816)*256 + t, rpe, rct2, 2048, 1);
  } else if (blk < 3968) {
    // kvw transpose: wt[c][o] = kvw[o][c]   (512x256 -> 256x512)
    int base = ((blk-3840)*256 + t)*4;
    float4 vv = *(const float4*)(kvw + base);
    int o = base >> 8, c = base & 255;
    wt[(c+0)*512 + o] = vv.x;
    wt[(c+1)*512 + o] = vv.y;
    wt[(c+2)*512 + o] = vv.z;
    wt[(c+3)*512 + o] = vv.w;
  } else {
    // qw transpose: qwt[c][oc] = qw[oc][c]  (128x256 -> 256x128)
    int base = ((blk-3968)*256 + t)*4;
    float4 vv = *(const float4*)(qw + base);
    int oc = base >> 8, c = base & 255;
    qwt[(c+0)*128 + oc] = vv.x;
    qwt[(c+1)*128 + oc] = vv.y;
    qwt[(c+2)*128 + oc] = vv.z;
    qwt[(c+3)*128 + oc] = vv.w;
  }
}

// ---------- stage 2: fused local 3x3 + kv 1x1 (both branches) + q 1x1 ----------
// blocks [0,64): br1 strips, [64,320): br2 strips, [320,832): q conv.
__global__ void __launch_bounds__(256) localkv_kernel(
    const float* __restrict__ t1in, const float* __restrict__ t2in,
    const float* __restrict__ lw, const float* __restrict__ lb,
    const float* __restrict__ wt, const float* __restrict__ kvb,
    u16* __restrict__ kt1, u16* __restrict__ vt1,
    u16* __restrict__ kt2, u16* __restrict__ vt2,
    const float* __restrict__ x, const float* __restrict__ qwt,
    const float* __restrict__ qb, u16* __restrict__ q) {
  __shared__ float sbuf[NC*16];
  int blk = blockIdx.x, tid = threadIdx.x;
  if (blk < 320) {
    // ---- fused local+kv over an 8-spatial strip ----
    const float* tin; u16 *kT, *vT; int OH, hw, b, s0;
    if (blk < 64) { tin = t1in; kT = kt1; vT = vt1; OH = 16; hw = 256;  b = blk >> 5;  s0 = (blk & 31)*8; }
    else { int v = blk-64; tin = t2in; kT = kt2; vT = vt2; OH = 32; hw = 1024; b = v >> 7; s0 = (v & 127)*8; }
    int oy = s0 / OH, ox0 = s0 % OH;
    // stage A: y(strip) -> LDS, stride 12 (broadcast-friendly, 16B aligned)
    int ci = tid >> 3, i = tid & 7;
    int ox = ox0 + i;
    #pragma unroll
    for (int p = 0; p < 8; ++p) {
      int c = p*32 + ci;
      const float* tp = tin + (b*NC + c)*hw;
      const float* wp = lw + c*9;
      float acc = lb[c];
      #pragma unroll
      for (int dy = 0; dy < 3; ++dy) {
        int iy = oy + dy - 1;
        if (iy < 0 || iy >= OH) continue;
        #pragma unroll
        for (int dx = 0; dx < 3; ++dx) {
          int ix = ox + dx - 1;
          if (ix < 0 || ix >= OH) continue;
          acc += tp[iy*OH + ix]*wp[dy*3 + dx];
        }
      }
      acc += tp[oy*OH + ox];
      sbuf[c*12 + i] = acc;
    }
    __syncthreads();
    // stage B: kv conv; this thread computes K row (o=tid) and V row (o=tid+256)
    float acc0[8], acc1[8];
    float b0 = kvb[tid], b1 = kvb[tid + 256];
    #pragma unroll
    for (int j = 0; j < 8; ++j) { acc0[j] = b0; acc1[j] = b1; }
    #pragma unroll 4
    for (int c = 0; c < NC; ++c) {
      f32x4 ya = *(const f32x4*)(sbuf + c*12);
      f32x4 yb = *(const f32x4*)(sbuf + c*12 + 4);
      float w0 = wt[c*512 + tid];
      float w1 = wt[c*512 + tid + 256];
      #pragma unroll
      for (int j = 0; j < 4; ++j) {
        acc0[j]   += w0*ya[j];  acc0[4+j] += w0*yb[j];
        acc1[j]   += w1*ya[j];  acc1[4+j] += w1*yb[j];
      }
    }
    int hh2 = tid >> 6, r = tid & 63, d = r >> 1, e = r & 1;
    int L = 2*hw;
    u16* kp = kT + ((size_t)((b*NHH + hh2)*L + e*hw + s0))*ND + d;
    #pragma unroll
    for (int j = 0; j < 8; ++j) kp[j*ND] = f2bf(acc0[j]);
    u16* vp = vT + ((size_t)((b*NHH + hh2)*ND + d))*L + e*hw + s0;
    #pragma unroll
    for (int j = 0; j < 8; ++j) vp[j] = f2bf(acc1[j]);
  } else {
    // ---- q conv: 16 spatial/block, coalesced qwt weights ----
    int blk2 = blk - 320;           // 0..511
    int b = blk2 >> 8;
    int n0 = (blk2 & 255) * 16;
    #pragma unroll
    for (int j = 0; j < 16; ++j) {
      int idx = tid + 256*j;
      int c = idx >> 4, i = idx & 15;
      sbuf[idx] = x[(b*NC + c)*HWIN + n0 + i];
    }
    __syncthreads();
    int half = tid >> 7, oc = tid & 127;
    float bias = qb[oc];
    float acc[8];
    #pragma unroll
    for (int i = 0; i < 8; ++i) acc[i] = bias;
    #pragma unroll 4
    for (int c = 0; c < NC; ++c) {
      float w = qwt[c*128 + oc];     // coalesced across lanes
      #pragma unroll
      for (int i = 0; i < 8; ++i) acc[i] += w * sbuf[c*16 + half*8 + i];
    }
    int h = oc >> 5, d = oc & 31;
    u16* qp = q + (((size_t)(b*NHH + h))*NN + n0 + half*8)*ND + d;
    #pragma unroll
    for (int i = 0; i < 8; ++i) qp[i*ND] = f2bf(acc[i]*QSCALE);
  }
}

// ---------- stage 3: MFMA flash attention, single-buffered LDS K/V + reg prefetch ----------
// blocks [0,512): branch1 full L=512, direct write.
// blocks [512,2560): branch2, one of 4 L-chunks; writes bf16 partial O + ssum.
// LDS 23 KB/block -> ~7 blocks/CU (vs 4 with double-buffer).
__global__ void __launch_bounds__(256) attn_kernel(
    const u16* __restrict__ qbf,
    const u16* __restrict__ kt1, const u16* __restrict__ vt1, const u16* __restrict__ rct1,
    const u16* __restrict__ kt2, const u16* __restrict__ vt2, const u16* __restrict__ rct2,
    u32* __restrict__ po32, float* __restrict__ ps,
    float* __restrict__ out) {
  __shared__ u16 kbuf[64*72];          // K tile rows l, padded stride 72
  __shared__ u16 vbuf[32*72];          // V tile rows d, padded stride 72
  __shared__ u32 pbuf_all[4][16*36];   // per-wave P^T tile, u16-stride 72
  int u = blockIdx.x;
  int br, b, hh, rb, chunk;
  if (u < 512) { br = 0; b = u >> 8; hh = (u >> 6) & 3; rb = u & 63; chunk = 0; }
  else { int v = u - 512; br = 1; chunk = v & 3; rb = (v >> 2) & 63; hh = (v >> 8) & 3; b = v >> 10; }
  int L = br ? 2048 : 512;
  const u16* kT  = br ? kt2 : kt1;
  const u16* vT  = br ? vt2 : vt1;
  const u16* rcT = br ? rct2 : rct1;
  int l0base = chunk * 512;
  int tid = threadIdx.x;
  int w = tid >> 6, lane = tid & 63;
  int g = lane >> 4, lo = lane & 15;
  u32* pbuf = pbuf_all[w];
  u16* pbuf16 = (u16*)pbuf;
  int n = rb*64 + w*16 + lo;

  const u16* kbase = kT + (size_t)(b*NHH + hh)*L*ND;
  const u16* vbase = vT + (size_t)(b*NHH + hh)*ND*L;
  const u16* rcTb  = rcT + (size_t)b*L*80;

  // Q B-frag (pre-scaled by 1/sqrt(32)*log2e)
  short8 qf = *(const short8*)(qbf + (((size_t)(b*NHH + hh))*NN + n)*ND + 8*g);

  // tap-weight B-frag for RPE ext-MFMA
  float fr = ((float)n + 0.5f)*(1.f/64.f) - 0.5f;
  int ri0 = (int)floorf(fr) - 1;
  int a = (w < 2) ? rb - 2 : rb - 1;     // wave-uniform floor(fr(q0)) - 1
  int rmin = a & ~3;
  float wr4[4]; float wsum = 0.f;
  #pragma unroll
  for (int j = 0; j < 4; ++j) {
    int i = ri0 + j;
    float wv = (i >= 0 && i < 64) ? keysw(fr - (float)i) : 0.f;
    wr4[j] = wv; wsum += wv;
  }
  float invw = LOG2E / wsum;
  float wt8[8];
  #pragma unroll
  for (int s = 0; s < 8; ++s) {
    float acc = 0.f;
    #pragma unroll
    for (int j = 0; j < 4; ++j)
      acc += (ri0 + j - rmin == s) ? wr4[j]*invw : 0.f;
    wt8[s] = acc;
  }
  short8 wtf;
  {
    u32 p0 = pk_bf16(wt8[0], wt8[1]), p1 = pk_bf16(wt8[2], wt8[3]);
    u32 p2 = pk_bf16(wt8[4], wt8[5]), p3 = pk_bf16(wt8[6], wt8[7]);
    uint4 uu = make_uint4(p0, p1, p2, p3);
    wtf = __builtin_bit_cast(short8, uu);
    if (g != 0) wtf = (short8)0;
  }
  const u16* rcrow0 = rcTb + (rmin + 4);

  const f32x4 zero = {0.f, 0.f, 0.f, 0.f};
  float ssum = 0.f;
  f32x4 o0 = zero, o1 = zero;

  // staging lane roles
  int kr_row = tid >> 2, kr_col = (tid & 3)*8;   // K: 64 rows x 32
  int vr_row = tid >> 3, vr_col = (tid & 7)*8;   // V: 32 rows x 64

  auto stageLoad = [&](short8& kr, short8& vr, int l0) {
    kr = *(const short8*)(kbase + (size_t)(l0 + kr_row)*ND + kr_col);
    vr = *(const short8*)(vbase + (size_t)vr_row*L + l0 + vr_col);
  };
  auto stageStore = [&](short8 kr, short8 vr) {
    *(short8*)(kbuf + kr_row*72 + kr_col) = kr;
    *(short8*)(vbuf + vr_row*72 + vr_col) = vr;
  };
  auto loadRC = [&](uint4 (&rc)[4], int l0) {
    #pragma unroll
    for (int c = 0; c < 4; ++c) {
      const u16* arow = rcrow0 + (size_t)(l0 + 16*c + lo)*80;
      uint2 ra = *(const uint2*)arow;
      uint2 rb2 = *(const uint2*)(arow + 4);
      rc[c] = make_uint4(ra.x, ra.y, rb2.x, rb2.y);
    }
  };

  short8 kr, vr;
  uint4 rcA[4], rcB[4];
  stageLoad(kr, vr, l0base);
  loadRC(rcA, l0base);

  for (int t = 0; t < 8; ++t) {
    stageStore(kr, vr);
    __syncthreads();
    if (t < 7) { stageLoad(kr, vr, l0base + (t+1)*64); loadRC(rcB, l0base + (t+1)*64); }
    // S tiles: rc ext-MFMA chained into K.Q MFMA
    f32x4 s4[4];
    #pragma unroll
    for (int c = 0; c < 4; ++c) {
      short8 rcf = __builtin_bit_cast(short8, rcA[c]);
      f32x4 accr = __builtin_amdgcn_mfma_f32_16x16x32_bf16(rcf, wtf, zero, 0, 0, 0);
      short8 kf = *(const short8*)(kbuf + (16*c + lo)*72 + 8*g);
      s4[c] = __builtin_amdgcn_mfma_f32_16x16x32_bf16(kf, qf, accr, 0, 0, 0);
    }
    // max-free softmax: p = exp2(s)
    float psum = 0.f;
    u32 pk[8];
    #pragma unroll
    for (int c = 0; c < 4; ++c) {
      float p0 = exp2f(s4[c][0]), p1 = exp2f(s4[c][1]);
      float p2 = exp2f(s4[c][2]), p3 = exp2f(s4[c][3]);
      psum += (p0 + p1) + (p2 + p3);
      pk[2*c]   = pk_bf16(p0, p1);
      pk[2*c+1] = pk_bf16(p2, p3);
    }
    ssum += psum;
    #pragma unroll
    for (int c = 0; c < 4; ++c)
      *(uint2*)(pbuf + lo*36 + 8*c + 2*g) = make_uint2(pk[2*c], pk[2*c+1]);
    short8 pf0 = *(const short8*)(pbuf16 + lo*72 + 8*g);
    short8 pf1 = *(const short8*)(pbuf16 + lo*72 + 32 + 8*g);
    short8 v00 = *(const short8*)(vbuf + lo*72 + 8*g);
    short8 v01 = *(const short8*)(vbuf + lo*72 + 32 + 8*g);
    short8 v10 = *(const short8*)(vbuf + (16+lo)*72 + 8*g);
    short8 v11 = *(const short8*)(vbuf + (16+lo)*72 + 32 + 8*g);
    o0 = __builtin_amdgcn_mfma_f32_16x16x32_bf16(v00, pf0, o0, 0, 0, 0);
    o1 = __builtin_amdgcn_mfma_f32_16x16x32_bf16(v10, pf0, o1, 0, 0, 0);
    o0 = __builtin_amdgcn_mfma_f32_16x16x32_bf16(v01, pf1, o0, 0, 0, 0);
    o1 = __builtin_amdgcn_mfma_f32_16x16x32_bf16(v11, pf1, o1, 0, 0, 0);
    if (t < 7) {
      #pragma unroll
      for (int j = 0; j < 4; ++j) rcA[j] = rcB[j];
    }
    __syncthreads();   // all reads done before next tile's store
  }

  ssum += __shfl_xor(ssum, 16, 64);
  ssum += __shfl_xor(ssum, 32, 64);
  if (br == 0) {
    float inv = 1.f/ssum;
    f32x4 w0 = o0*inv, w1 = o1*inv;
    float* op = out + ((size_t)((b*NC + hh*64 + rb)*64 + (w*16 + lo)))*64;
    *(f32x4*)(op + 4*g)      = w0;
    *(f32x4*)(op + 16 + 4*g) = w1;
  } else {
    int bh = b*NHH + hh;
    int row = bh*NN + n;
    u32* pop = po32 + ((size_t)chunk*32768 + row)*16;    // chunk-major
    pop[2*g]     = pk_bf16(o0[0], o0[1]);
    pop[2*g + 1] = pk_bf16(o0[2], o0[3]);
    pop[8 + 2*g]     = pk_bf16(o1[0], o1[1]);
    pop[8 + 2*g + 1] = pk_bf16(o1[2], o1[3]);
    if (g == 0) ps[(size_t)chunk*32768 + row] = ssum;
  }
}

// ---------- stage 4: combine branch-2 chunk partials (coalesced, 4 thr/row) ----------
__global__ void __launch_bounds__(256) combine_kernel(
    const u32* __restrict__ po32, const float* __restrict__ ps,
    float* __restrict__ out) {
  int gid = blockIdx.x*256 + threadIdx.x;   // 0..131071
  int row = gid >> 2, part = gid & 3;       // row 0..32767; part = 8-float group
  float sden = ps[row] + ps[32768 + row] + ps[65536 + row] + ps[98304 + row];
  float inv = 1.f/sden;
  float o[8];
  #pragma unroll
  for (int i = 0; i < 8; ++i) o[i] = 0.f;
  #pragma unroll
  for (int chunk = 0; chunk < 4; ++chunk) {
    const u32* pp = po32 + ((size_t)chunk*32768 + row)*16 + part*4;
    uint4 a = *(const uint4*)pp;            // coalesced 16B
    u32 av[4] = {a.x, a.y, a.z, a.w};
    #pragma unroll
    for (int j = 0; j < 4; ++j) {
      o[2*j]   += __uint_as_float(av[j] << 16);
      o[2*j+1] += __uint_as_float(av[j] & 0xffff0000u);
    }
  }
  int bh = row >> 12, n = row & 4095;
  float* op = out + ((size_t)(((bh>>2)*NC + (bh&3)*64 + (n>>6))*64 + (n&63)))*64 + 32 + part*8;
  #pragma unroll
  for (int j = 0; j < 2; ++j) {
    f32x4 v = {o[4*j]*inv, o[4*j+1]*inv, o[4*j+2]*inv, o[4*j+3]*inv};
    *(f32x4*)(op + 4*j) = v;
  }
}

extern "C" void kernel_launch(void* const* d_in, const int* in_sizes, int n_in,
                              void* d_out, int out_size, void* d_ws, size_t ws_size,
                              hipStream_t stream) {
  const float* x    = (const float*)d_in[0];
  const float* rpe  = (const float*)d_in[1];
  const float* qw   = (const float*)d_in[2];
  const float* qb   = (const float*)d_in[3];
  const float* kvw  = (const float*)d_in[4];
  const float* kvb  = (const float*)d_in[5];
  const float* dw1  = (const float*)d_in[6];
  const float* bn11 = (const float*)d_in[7];
  const float* pw1  = (const float*)d_in[8];
  const float* bn12 = (const float*)d_in[9];
  const float* dw2  = (const float*)d_in[10];
  const float* bn21 = (const float*)d_in[11];
  const float* pw2  = (const float*)d_in[12];
  const float* bn22 = (const float*)d_in[13];
  const float* lw   = (const float*)d_in[14];
  const float* lb   = (const float*)d_in[15];
  float* out = (float*)d_out;
  float* ws  = (float*)d_ws;

  float* t1   = ws + OFF_T1;
  float* t2   = ws + OFF_T2;
  u16*   q    = (u16*)(ws + OFF_Q);
  u16*   kt1  = (u16*)(ws + OFF_KT1);
  u16*   vt1  = (u16*)(ws + OFF_VT1);
  u16*   kt2  = (u16*)(ws + OFF_KT2);
  u16*   vt2  = (u16*)(ws + OFF_VT2);
  u16*   rct1 = (u16*)(ws + OFF_RCT1);
  u16*   rct2 = (u16*)(ws + OFF_RCT2);
  float* wt   = ws + OFF_WT;
  u32*   po32 = (u32*)(ws + OFF_PO);
  float* ps   = ws + OFF_PS;
  float* qwt  = ws + OFF_QWT;

  hipLaunchKernelGGL(prep_kernel, dim3(4000), dim3(256), 0, stream,
                     x, dw1, bn11, pw1, bn12, t1, dw2, bn21, pw2, bn22, t2,
                     rpe, rct1, rct2, kvw, wt, qw, qwt);
  hipLaunchKernelGGL(localkv_kernel, dim3(832), dim3(256), 0, stream,
                     t1, t2, lw, lb, wt, kvb, kt1, vt1, kt2, vt2, x, qwt, qb, q);
  hipLaunchKernelGGL(attn_kernel, dim3(2560), dim3(256), 0, stream,
                     q, kt1, vt1, rct1, kt2, vt2, rct2, po32, ps, out);
  hipLaunchKernelGGL(combine_kernel, dim3(512), dim3(256), 0, stream,
                     po32, ps, out);
}